// Round 15
// baseline (182.176 us; speedup 1.0000x reference)
//
#include <hip/hip_runtime.h>
#include <hip/hip_bf16.h>
#include <cstdint>

using u16 = unsigned short;
typedef short bf16x8 __attribute__((ext_vector_type(8)));
typedef float f32x4 __attribute__((ext_vector_type(4)));
typedef float f32x16 __attribute__((ext_vector_type(16)));
typedef u16 u16x4 __attribute__((ext_vector_type(4)));
typedef u16 u16x8 __attribute__((ext_vector_type(8)));

// ---------- helpers ----------
__device__ __forceinline__ u16 f2bf(float f) {
  union { float f; uint32_t u; } v; v.f = f;
  uint32_t r = (v.u + 0x7fffu + ((v.u >> 16) & 1u)) >> 16;  // RNE
  return (u16)r;
}

__device__ __forceinline__ float bf2f(u16 u) {
  union { uint32_t u; float f; } v; v.u = (uint32_t)u << 16; return v.f;
}

__device__ __forceinline__ void async16(const void* g, void* l) {
  __builtin_amdgcn_global_load_lds(
      (const __attribute__((address_space(1))) uint32_t*)g,
      (__attribute__((address_space(3))) uint32_t*)l, 16, 0, 0);
}

__device__ __forceinline__ uint32_t cvtpk(float a, float b) {
  uint32_t r;
  asm("v_cvt_pk_bf16_f32 %0, %1, %2" : "=v"(r) : "v"(a), "v"(b));
  return r;
}

// swap upper 32 lanes of a with lower 32 lanes of b (validated in PV path since r2)
__device__ __forceinline__ void plswap(uint32_t& a, uint32_t& b) {
  asm volatile("v_permlane32_swap_b32 %0, %1" : "+v"(a), "+v"(b));
}

// ---------- fused prep: cvt x (blocks 0..4095) + 4x weight transpose (4096..5119) ----------
__global__ __launch_bounds__(256) void prep_kernel(
    const float* __restrict__ x, const float* __restrict__ wq, const float* __restrict__ wk,
    const float* __restrict__ wv, const float* __restrict__ wo,
    u16* __restrict__ xb, u16* __restrict__ Wqt, u16* __restrict__ Wkt,
    u16* __restrict__ Wvt, u16* __restrict__ Wot) {
  __shared__ float tile[64][65];
  const int tid = threadIdx.x;
  const int bid = blockIdx.x;
  if (bid < 4096) {
    int i = (bid * 256 + tid) * 4;
    float4 v = *(const float4*)(x + i);
    u16x4 o;
    o[0] = f2bf(v.x); o[1] = f2bf(v.y); o[2] = f2bf(v.z); o[3] = f2bf(v.w);
    *(u16x4*)(xb + i) = o;
    return;
  }
  const int id = bid - 4096;
  const int wsel = id >> 8, sub = id & 255;
  const float* W = (wsel == 0) ? wq : (wsel == 1) ? wk : (wsel == 2) ? wv : wo;
  u16* Wt = (wsel == 0) ? Wqt : (wsel == 1) ? Wkt : (wsel == 2) ? Wvt : Wot;
  const int k0 = (sub & 15) * 64, n0 = (sub >> 4) * 64;
#pragma unroll
  for (int i = 0; i < 4; ++i) {
    int c = i * 256 + tid;
    int r = c >> 4, c4 = c & 15;
    float4 v = *(const float4*)(W + (size_t)(k0 + r) * 1024 + n0 + c4 * 4);
    tile[r][c4 * 4 + 0] = v.x; tile[r][c4 * 4 + 1] = v.y;
    tile[r][c4 * 4 + 2] = v.z; tile[r][c4 * 4 + 3] = v.w;
  }
  __syncthreads();
#pragma unroll
  for (int i = 0; i < 2; ++i) {
    int c = i * 256 + tid;
    int n = c >> 3, kc = c & 7;
    u16x8 o;
#pragma unroll
    for (int j = 0; j < 8; ++j) o[j] = f2bf(tile[kc * 8 + j][n]);
    *(u16x8*)(Wt + (size_t)(n0 + n) * 1024 + k0 + kc * 8) = o;
  }
}

// ---------- 8-wave GEMM mainloop: C(128x128) = A(128xK) * Bt(128xK)^T, K=1024 ----------
__device__ __forceinline__ void stage8(const u16* A, const u16* Bt, int m0, int n0, int kt,
                                       u16* As, u16* Bs, int tid) {
  int row = tid >> 2, cc = tid & 3;
  int koff = kt * 32 + ((cc ^ (row & 3)) << 3);
  async16(A + (size_t)(m0 + row) * 1024 + koff, As + (size_t)tid * 8);
  async16(Bt + (size_t)(n0 + row) * 1024 + koff, Bs + (size_t)tid * 8);
}

__device__ __forceinline__ void gemm_mainloop8(const u16* A, const u16* Bt, int m0, int n0,
                                               u16 (*As)[4096], u16 (*Bs)[4096], f32x4 acc[4][2]) {
  const int tid = threadIdx.x, w = tid >> 6, lane = tid & 63, lo = lane & 15, hi = lane >> 4;
  const int mb = (w >> 2) * 64;
  const int cb = ((w >> 1) & 1) * 64 + (w & 1) * 16;
  stage8(A, Bt, m0, n0, 0, As[0], Bs[0], tid);
  __syncthreads();
  for (int kt = 0; kt < 32; ++kt) {
    int cur = kt & 1;
    if (kt + 1 < 32) stage8(A, Bt, m0, n0, kt + 1, As[cur ^ 1], Bs[cur ^ 1], tid);
    const int sw = (hi ^ (lo & 3)) << 3;
    bf16x8 af[4], bfr[2];
#pragma unroll
    for (int i = 0; i < 4; ++i) af[i] = *(const bf16x8*)(As[cur] + (mb + i * 16 + lo) * 32 + sw);
#pragma unroll
    for (int j = 0; j < 2; ++j) bfr[j] = *(const bf16x8*)(Bs[cur] + (cb + j * 32 + lo) * 32 + sw);
#pragma unroll
    for (int i = 0; i < 4; ++i)
#pragma unroll
      for (int j = 0; j < 2; ++j)
        acc[i][j] = __builtin_amdgcn_mfma_f32_16x16x32_bf16(af[i], bfr[j], acc[i][j], 0, 0, 0);
    __syncthreads();
  }
}

// ---------- FUSED QKV projection + RoPE + scatter (8-wave) ----------
__global__ __launch_bounds__(512, 4) void qkv_gemm_kernel(
    const u16* __restrict__ xb, const u16* __restrict__ Wcat,
    u16* __restrict__ Qf, u16* __restrict__ Kf, u16* __restrict__ Vf) {
  __shared__ u16 As[2][4096];
  __shared__ u16 Bs[2][4096];
  const int m0 = blockIdx.x * 128, n0 = blockIdx.y * 128;
  const int mode = n0 >> 10, nloc = n0 & 1023;
  f32x4 acc[4][2];
  const f32x4 z4 = {0.f, 0.f, 0.f, 0.f};
#pragma unroll
  for (int i = 0; i < 4; ++i)
#pragma unroll
    for (int j = 0; j < 2; ++j) acc[i][j] = z4;
  gemm_mainloop8(xb, Wcat, m0, n0, As, Bs, acc);

  const int tid = threadIdx.x, w = tid >> 6, lane = tid & 63, lo = lane & 15, hi = lane >> 4;
  const int c1 = (w >> 1) & 1, c2 = w & 1;
  const int h = (nloc >> 6) + c1;
  const int mrow0 = m0 + (w >> 2) * 64;
  if (mode < 2) {
    u16* Out = (mode == 0) ? Qf : Kf;
    const float qscale = (mode == 0) ? 0.18033688011112042f : 1.0f;
    const float invf = exp2f(-(float)(c2 * 16 + lo) * 0.41524101186092034f);
    const int lnoff = (lo >> 3) * 256 + (lo & 7) + c2 * 512;
#pragma unroll
    for (int mi = 0; mi < 4; ++mi) {
#pragma unroll
      for (int r = 0; r < 4; ++r) {
        int tg = mrow0 + mi * 16 + hi * 4 + r;
        int b = tg >> 11, tp = tg & 2047;
        float cs, sn;
        __sincosf((float)tp * invf, &sn, &cs);
        size_t obase = (size_t)((b * 16 + h) * 64 + (tp >> 5)) * 2048 + (size_t)(tp & 31) * 8 + lnoff;
        float v0 = acc[mi][0][r], v1 = acc[mi][1][r];
        Out[obase]        = f2bf((v0 * cs - v1 * sn) * qscale);
        Out[obase + 1024] = f2bf((v1 * cs + v0 * sn) * qscale);
      }
    }
  } else {
#pragma unroll
    for (int mi = 0; mi < 4; ++mi) {
      int tg0 = mrow0 + mi * 16 + hi * 4;
      int b = tg0 >> 11, tp0 = tg0 & 2047;
#pragma unroll
      for (int j = 0; j < 2; ++j) {
        int d = c2 * 16 + j * 32 + lo;
        u16x4 pk;
#pragma unroll
        for (int r = 0; r < 4; ++r) pk[r] = f2bf(acc[mi][j][r]);
        *(u16x4*)(Vf + ((size_t)((b * 16 + h) * 256 + (tp0 >> 3)) * 64 + d) * 8 + (tp0 & 7)) = pk;
      }
    }
  }
}

// ---------- flash attention: 4 independent waves, FIXED-m softmax, SINGLE K set ----------
// grid (bh=32, qi=64), 256 thr. Wave p takes a quarter of g's 64-key tiles.
// K prefetch uses ONE register set: QK's MFMAs consume kA/kB at issue, so
// LOADK(t+1) right after them overwrites freely and its L2 latency (~200cy)
// hides under mask/exp/pack/PV (~400cy). Saves 16 VGPR vs the r11/r14 double
// set -> more resident waves. launch_bounds(256,4): cap 128 VGPR (r9-vs-r11
// evidence: higher residency beat lower-VGPR-pressure at this chain length).
__global__ __launch_bounds__(256, 4) void attn_kernel(const u16* __restrict__ Qf, const u16* __restrict__ Kf,
                                                      const u16* __restrict__ Vf, u16* __restrict__ ctx) {
  __shared__ u16 Omb[3][32 * 68];
  __shared__ float Lsm[3][32];
  const int bh = blockIdx.x, qi = blockIdx.y;
  const int g = (qi & ~7) | (((qi >> 3) & 1) ? (7 - (qi & 7)) : (qi & 7));
  const int tid = threadIdx.x, p = tid >> 6, lane = tid & 63;
  const int lo5 = lane & 31, hi = lane >> 5;
  const int nt = (g >> 1) + 1;
  const int qq = nt >> 2, rem = nt & 3;
  const int cnt = qq + (p < rem ? 1 : 0);
  const int t0 = p * qq + (p < rem ? p : rem);
  const int bb = bh >> 4, h = bh & 15;

  const u16* Qb = Qf + (size_t)bh * 131072 + (size_t)g * 2048 + lane * 8;
  const u16* Kb = Kf + (size_t)bh * 131072 + lane * 8;
  const u16* Vb = Vf + (size_t)bh * 131072 + hi * 512 + lo5 * 8;

  bf16x8 qf[4];
#pragma unroll
  for (int d = 0; d < 4; ++d) qf[d] = *(const bf16x8*)(Qb + d * 512);

  f32x16 O0, O1;
#pragma unroll
  for (int r = 0; r < 16; ++r) { O0[r] = 0.f; O1[r] = 0.f; }
  float l_run = 0.f;

  bf16x8 kA[4], kB[4];  // single K register set

  auto LOADK = [&](int t) {
    const u16* kt = Kb + (size_t)t * 4096;
#pragma unroll
    for (int d = 0; d < 4; ++d) {
      kA[d] = *(const bf16x8*)(kt + d * 512);
      kB[d] = *(const bf16x8*)(kt + 2048 + d * 512);
    }
  };

  if (cnt > 0) {
    LOADK(t0);
    for (int i = 0; i < cnt; ++i) {
      const int t = t0 + i;
      f32x16 s0, s1;
#pragma unroll
      for (int r = 0; r < 16; ++r) { s0[r] = 0.f; s1[r] = 0.f; }
      __builtin_amdgcn_s_setprio(1);
#pragma unroll
      for (int d = 0; d < 4; ++d) {
        s0 = __builtin_amdgcn_mfma_f32_32x32x16_bf16(kA[d], qf[d], s0, 0, 0, 0);
        s1 = __builtin_amdgcn_mfma_f32_32x32x16_bf16(kB[d], qf[d], s1, 0, 0, 0);
      }
      __builtin_amdgcn_s_setprio(0);

      // prefetch next K into the SAME set (QK consumed it); overlaps exp/pack/PV
      if (i + 1 < cnt) LOADK(t + 1);

      // V loads: exp/pack below cover their L2 latency
      const u16* vt = Vb + (size_t)t * 4096;
      bf16x8 vA[4], vB[4];
#pragma unroll
      for (int ks = 0; ks < 4; ++ks) {
        vA[ks] = *(const bf16x8*)(vt + ks * 1024);
        vB[ks] = *(const bf16x8*)(vt + ks * 1024 + 256);
      }

      if (t == nt - 1) {
#pragma unroll
        for (int r = 0; r < 16; ++r) {
          int kl = (r & 3) + 8 * (r >> 2) + 4 * hi;
          if (g & 1) {
            if (kl > lo5) s1[r] = -1e30f;
          } else {
            if (kl > lo5) s0[r] = -1e30f;
            s1[r] = -1e30f;
          }
        }
      }

      float sm[16];
#pragma unroll
      for (int r = 0; r < 16; ++r) {
        float p0 = exp2f(s0[r]); s0[r] = p0;
        float p1 = exp2f(s1[r]); s1[r] = p1;
        sm[r] = p0 + p1;
      }
#pragma unroll
      for (int d = 8; d; d >>= 1)
#pragma unroll
        for (int r = 0; r < d; ++r) sm[r] += sm[r + d];
      l_run += sm[0];

      uint32_t W0[8], W1[8];
#pragma unroll
      for (int i2 = 0; i2 < 8; ++i2) {
        W0[i2] = cvtpk(s0[2 * i2], s0[2 * i2 + 1]);
        W1[i2] = cvtpk(s1[2 * i2], s1[2 * i2 + 1]);
      }
      __builtin_amdgcn_s_setprio(1);
#pragma unroll
      for (int ks = 0; ks < 4; ++ks) {
        uint32_t a, d2, c2, e2;
        if (ks == 0)      { a = W0[0]; d2 = W0[1]; c2 = W0[2]; e2 = W0[3]; }
        else if (ks == 1) { a = W0[4]; d2 = W0[5]; c2 = W0[6]; e2 = W0[7]; }
        else if (ks == 2) { a = W1[0]; d2 = W1[1]; c2 = W1[2]; e2 = W1[3]; }
        else              { a = W1[4]; d2 = W1[5]; c2 = W1[6]; e2 = W1[7]; }
        plswap(a, c2);
        plswap(d2, e2);
        union { uint32_t u[4]; bf16x8 v; } f;
        f.u[0] = a; f.u[1] = d2; f.u[2] = c2; f.u[3] = e2;
        O0 = __builtin_amdgcn_mfma_f32_32x32x16_bf16(vA[ks], f.v, O0, 0, 0, 0);
        O1 = __builtin_amdgcn_mfma_f32_32x32x16_bf16(vB[ks], f.v, O1, 0, 0, 0);
      }
      __builtin_amdgcn_s_setprio(0);
    }
  }

  l_run += __shfl_xor(l_run, 32);

  if (p != 0) {
    u16* om = Omb[p - 1] + (size_t)lo5 * 68;
#pragma unroll
    for (int gg = 0; gg < 4; ++gg) {
      int off = 8 * gg + 4 * hi;
      u16x4 w0, w1;
#pragma unroll
      for (int j = 0; j < 4; ++j) { w0[j] = f2bf(O0[4 * gg + j]); w1[j] = f2bf(O1[4 * gg + j]); }
      *(u16x4*)(om + off) = w0;
      *(u16x4*)(om + 32 + off) = w1;
    }
    if (hi == 0) Lsm[p - 1][lo5] = l_run;
  }
  __syncthreads();
  if (p == 0) {
    float invl = 1.0f / (l_run + Lsm[0][lo5] + Lsm[1][lo5] + Lsm[2][lo5]);
    const u16* om1 = Omb[0] + (size_t)lo5 * 68;
    const u16* om2 = Omb[1] + (size_t)lo5 * 68;
    const u16* om3 = Omb[2] + (size_t)lo5 * 68;
    const int tq = 32 * g + lo5;
    size_t rowb = ((size_t)(bb * 2048 + tq)) * 1024 + h * 64;
#pragma unroll
    for (int gg = 0; gg < 4; ++gg) {
      int off = 8 * gg + 4 * hi;
      u16x4 q1 = *(const u16x4*)(om1 + off), q2 = *(const u16x4*)(om2 + off), q3 = *(const u16x4*)(om3 + off);
      u16x4 pk;
#pragma unroll
      for (int j = 0; j < 4; ++j)
        pk[j] = f2bf((O0[4 * gg + j] + bf2f(q1[j]) + bf2f(q2[j]) + bf2f(q3[j])) * invl);
      *(u16x4*)(ctx + rowb + off) = pk;
      u16x4 r1 = *(const u16x4*)(om1 + 32 + off), r2 = *(const u16x4*)(om2 + 32 + off), r3 = *(const u16x4*)(om3 + 32 + off);
#pragma unroll
      for (int j = 0; j < 4; ++j)
        pk[j] = f2bf((O1[4 * gg + j] + bf2f(r1[j]) + bf2f(r2[j]) + bf2f(r3[j])) * invl);
      *(u16x4*)(ctx + rowb + 32 + off) = pk;
    }
  }
}

// ---------- output projection (8-wave): out = ctx @ w_o (f32 out) ----------
__global__ __launch_bounds__(512, 4) void out_gemm_kernel(const u16* __restrict__ ctxb,
                                                          const u16* __restrict__ Wot,
                                                          float* __restrict__ out) {
  __shared__ u16 As[2][4096];
  __shared__ u16 Bs[2][4096];
  const int m0 = blockIdx.x * 128, n0 = blockIdx.y * 128;
  f32x4 acc[4][2];
  const f32x4 z4 = {0.f, 0.f, 0.f, 0.f};
#pragma unroll
  for (int i = 0; i < 4; ++i)
#pragma unroll
    for (int j = 0; j < 2; ++j) acc[i][j] = z4;
  gemm_mainloop8(ctxb, Wot, m0, n0, As, Bs, acc);
  const int tid = threadIdx.x, w = tid >> 6, lane = tid & 63, lo = lane & 15, hi = lane >> 4;
  const int colb = n0 + ((w >> 1) & 1) * 64 + (w & 1) * 16;
#pragma unroll
  for (int mi = 0; mi < 4; ++mi)
#pragma unroll
    for (int r = 0; r < 4; ++r) {
      int tg = m0 + (w >> 2) * 64 + mi * 16 + hi * 4 + r;
      out[(size_t)tg * 1024 + colb + lo] = acc[mi][0][r];
      out[(size_t)tg * 1024 + colb + 32 + lo] = acc[mi][1][r];
    }
}

// ---------- launch ----------
extern "C" void kernel_launch(void* const* d_in, const int* in_sizes, int n_in,
                              void* d_out, int out_size, void* d_ws, size_t ws_size,
                              hipStream_t stream) {
  (void)in_sizes; (void)n_in; (void)out_size; (void)ws_size;
  const float* x  = (const float*)d_in[0];
  const float* wq = (const float*)d_in[1];
  const float* wk = (const float*)d_in[2];
  const float* wv = (const float*)d_in[3];
  const float* wo = (const float*)d_in[4];
  char* ws = (char*)d_ws;
  u16* xb   = (u16*)(ws + (size_t)0);
  u16* Wqt  = (u16*)(ws + ((size_t)8  << 20));   // Wqt/Wkt/Wvt contiguous: 3072x1024
  u16* Wkt  = (u16*)(ws + ((size_t)10 << 20));
  u16* Wvt  = (u16*)(ws + ((size_t)12 << 20));
  u16* Wot  = (u16*)(ws + ((size_t)14 << 20));
  u16* Qf   = (u16*)(ws + ((size_t)16 << 20));
  u16* Kf   = (u16*)(ws + ((size_t)24 << 20));
  u16* Vf   = (u16*)(ws + ((size_t)32 << 20));
  u16* ctxb = (u16*)(ws + ((size_t)40 << 20));

  prep_kernel<<<5120, 256, 0, stream>>>(x, wq, wk, wv, wo, xb, Wqt, Wkt, Wvt, Wot);
  qkv_gemm_kernel<<<dim3(32, 24), 512, 0, stream>>>(xb, Wqt, Qf, Kf, Vf);
  attn_kernel<<<dim3(32, 64), 256, 0, stream>>>(Qf, Kf, Vf, ctxb);
  out_gemm_kernel<<<dim3(32, 8), 512, 0, stream>>>(ctxb, Wot, (float*)d_out);
}

// Round 16
// 106.158 us; speedup vs baseline: 1.7161x; 1.7161x over previous
//
#include <hip/hip_runtime.h>
#include <hip/hip_bf16.h>
#include <cstdint>

using u16 = unsigned short;
typedef short bf16x8 __attribute__((ext_vector_type(8)));
typedef float f32x4 __attribute__((ext_vector_type(4)));
typedef float f32x16 __attribute__((ext_vector_type(16)));
typedef u16 u16x4 __attribute__((ext_vector_type(4)));
typedef u16 u16x8 __attribute__((ext_vector_type(8)));

// ---------- helpers ----------
__device__ __forceinline__ u16 f2bf(float f) {
  union { float f; uint32_t u; } v; v.f = f;
  uint32_t r = (v.u + 0x7fffu + ((v.u >> 16) & 1u)) >> 16;  // RNE
  return (u16)r;
}

__device__ __forceinline__ float bf2f(u16 u) {
  union { uint32_t u; float f; } v; v.u = (uint32_t)u << 16; return v.f;
}

__device__ __forceinline__ void async16(const void* g, void* l) {
  __builtin_amdgcn_global_load_lds(
      (const __attribute__((address_space(1))) uint32_t*)g,
      (__attribute__((address_space(3))) uint32_t*)l, 16, 0, 0);
}

__device__ __forceinline__ uint32_t cvtpk(float a, float b) {
  uint32_t r;
  asm("v_cvt_pk_bf16_f32 %0, %1, %2" : "=v"(r) : "v"(a), "v"(b));
  return r;
}

// swap upper 32 lanes of a with lower 32 lanes of b (validated in PV path since r2)
__device__ __forceinline__ void plswap(uint32_t& a, uint32_t& b) {
  asm volatile("v_permlane32_swap_b32 %0, %1" : "+v"(a), "+v"(b));
}

// ---------- fused prep: cvt x (blocks 0..4095) + 4x weight transpose (4096..5119) ----------
__global__ __launch_bounds__(256) void prep_kernel(
    const float* __restrict__ x, const float* __restrict__ wq, const float* __restrict__ wk,
    const float* __restrict__ wv, const float* __restrict__ wo,
    u16* __restrict__ xb, u16* __restrict__ Wqt, u16* __restrict__ Wkt,
    u16* __restrict__ Wvt, u16* __restrict__ Wot) {
  __shared__ float tile[64][65];
  const int tid = threadIdx.x;
  const int bid = blockIdx.x;
  if (bid < 4096) {
    int i = (bid * 256 + tid) * 4;
    float4 v = *(const float4*)(x + i);
    u16x4 o;
    o[0] = f2bf(v.x); o[1] = f2bf(v.y); o[2] = f2bf(v.z); o[3] = f2bf(v.w);
    *(u16x4*)(xb + i) = o;
    return;
  }
  const int id = bid - 4096;
  const int wsel = id >> 8, sub = id & 255;
  const float* W = (wsel == 0) ? wq : (wsel == 1) ? wk : (wsel == 2) ? wv : wo;
  u16* Wt = (wsel == 0) ? Wqt : (wsel == 1) ? Wkt : (wsel == 2) ? Wvt : Wot;
  const int k0 = (sub & 15) * 64, n0 = (sub >> 4) * 64;
#pragma unroll
  for (int i = 0; i < 4; ++i) {
    int c = i * 256 + tid;
    int r = c >> 4, c4 = c & 15;
    float4 v = *(const float4*)(W + (size_t)(k0 + r) * 1024 + n0 + c4 * 4);
    tile[r][c4 * 4 + 0] = v.x; tile[r][c4 * 4 + 1] = v.y;
    tile[r][c4 * 4 + 2] = v.z; tile[r][c4 * 4 + 3] = v.w;
  }
  __syncthreads();
#pragma unroll
  for (int i = 0; i < 2; ++i) {
    int c = i * 256 + tid;
    int n = c >> 3, kc = c & 7;
    u16x8 o;
#pragma unroll
    for (int j = 0; j < 8; ++j) o[j] = f2bf(tile[kc * 8 + j][n]);
    *(u16x8*)(Wt + (size_t)(n0 + n) * 1024 + k0 + kc * 8) = o;
  }
}

// ---------- 8-wave GEMM mainloop: C(128x128) = A(128xK) * Bt(128xK)^T, K=1024 ----------
__device__ __forceinline__ void stage8(const u16* A, const u16* Bt, int m0, int n0, int kt,
                                       u16* As, u16* Bs, int tid) {
  int row = tid >> 2, cc = tid & 3;
  int koff = kt * 32 + ((cc ^ (row & 3)) << 3);
  async16(A + (size_t)(m0 + row) * 1024 + koff, As + (size_t)tid * 8);
  async16(Bt + (size_t)(n0 + row) * 1024 + koff, Bs + (size_t)tid * 8);
}

__device__ __forceinline__ void gemm_mainloop8(const u16* A, const u16* Bt, int m0, int n0,
                                               u16 (*As)[4096], u16 (*Bs)[4096], f32x4 acc[4][2]) {
  const int tid = threadIdx.x, w = tid >> 6, lane = tid & 63, lo = lane & 15, hi = lane >> 4;
  const int mb = (w >> 2) * 64;
  const int cb = ((w >> 1) & 1) * 64 + (w & 1) * 16;
  stage8(A, Bt, m0, n0, 0, As[0], Bs[0], tid);
  __syncthreads();
  for (int kt = 0; kt < 32; ++kt) {
    int cur = kt & 1;
    if (kt + 1 < 32) stage8(A, Bt, m0, n0, kt + 1, As[cur ^ 1], Bs[cur ^ 1], tid);
    const int sw = (hi ^ (lo & 3)) << 3;
    bf16x8 af[4], bfr[2];
#pragma unroll
    for (int i = 0; i < 4; ++i) af[i] = *(const bf16x8*)(As[cur] + (mb + i * 16 + lo) * 32 + sw);
#pragma unroll
    for (int j = 0; j < 2; ++j) bfr[j] = *(const bf16x8*)(Bs[cur] + (cb + j * 32 + lo) * 32 + sw);
#pragma unroll
    for (int i = 0; i < 4; ++i)
#pragma unroll
      for (int j = 0; j < 2; ++j)
        acc[i][j] = __builtin_amdgcn_mfma_f32_16x16x32_bf16(af[i], bfr[j], acc[i][j], 0, 0, 0);
    __syncthreads();
  }
}

// ---------- FUSED QKV projection + RoPE + scatter (8-wave) ----------
__global__ __launch_bounds__(512, 4) void qkv_gemm_kernel(
    const u16* __restrict__ xb, const u16* __restrict__ Wcat,
    u16* __restrict__ Qf, u16* __restrict__ Kf, u16* __restrict__ Vf) {
  __shared__ u16 As[2][4096];
  __shared__ u16 Bs[2][4096];
  const int m0 = blockIdx.x * 128, n0 = blockIdx.y * 128;
  const int mode = n0 >> 10, nloc = n0 & 1023;
  f32x4 acc[4][2];
  const f32x4 z4 = {0.f, 0.f, 0.f, 0.f};
#pragma unroll
  for (int i = 0; i < 4; ++i)
#pragma unroll
    for (int j = 0; j < 2; ++j) acc[i][j] = z4;
  gemm_mainloop8(xb, Wcat, m0, n0, As, Bs, acc);

  const int tid = threadIdx.x, w = tid >> 6, lane = tid & 63, lo = lane & 15, hi = lane >> 4;
  const int c1 = (w >> 1) & 1, c2 = w & 1;
  const int h = (nloc >> 6) + c1;
  const int mrow0 = m0 + (w >> 2) * 64;
  if (mode < 2) {
    u16* Out = (mode == 0) ? Qf : Kf;
    const float qscale = (mode == 0) ? 0.18033688011112042f : 1.0f;
    const float invf = exp2f(-(float)(c2 * 16 + lo) * 0.41524101186092034f);
    const int lnoff = (lo >> 3) * 256 + (lo & 7) + c2 * 512;
#pragma unroll
    for (int mi = 0; mi < 4; ++mi) {
#pragma unroll
      for (int r = 0; r < 4; ++r) {
        int tg = mrow0 + mi * 16 + hi * 4 + r;
        int b = tg >> 11, tp = tg & 2047;
        float cs, sn;
        __sincosf((float)tp * invf, &sn, &cs);
        size_t obase = (size_t)((b * 16 + h) * 64 + (tp >> 5)) * 2048 + (size_t)(tp & 31) * 8 + lnoff;
        float v0 = acc[mi][0][r], v1 = acc[mi][1][r];
        Out[obase]        = f2bf((v0 * cs - v1 * sn) * qscale);
        Out[obase + 1024] = f2bf((v1 * cs + v0 * sn) * qscale);
      }
    }
  } else {
#pragma unroll
    for (int mi = 0; mi < 4; ++mi) {
      int tg0 = mrow0 + mi * 16 + hi * 4;
      int b = tg0 >> 11, tp0 = tg0 & 2047;
#pragma unroll
      for (int j = 0; j < 2; ++j) {
        int d = c2 * 16 + j * 32 + lo;
        u16x4 pk;
#pragma unroll
        for (int r = 0; r < 4; ++r) pk[r] = f2bf(acc[mi][j][r]);
        *(u16x4*)(Vf + ((size_t)((b * 16 + h) * 256 + (tp0 >> 3)) * 64 + d) * 8 + (tp0 & 7)) = pk;
      }
    }
  }
}

// ---------- flash attention: 4 independent waves, FIXED-m softmax (r14 config) ----------
// grid (bh=32, qi=64), 256 thr. Wave p takes a quarter of g's 64-key tiles.
// Double K named-set prefetch, (256,2) cap — measured 42us / VGPR 108 / no spill.
// (r15's single-set + (256,4) cap spilled to scratch: 285MB WRITE_SIZE. Reverted.)
__global__ __launch_bounds__(256, 2) void attn_kernel(const u16* __restrict__ Qf, const u16* __restrict__ Kf,
                                                      const u16* __restrict__ Vf, u16* __restrict__ ctx) {
  __shared__ u16 Omb[3][32 * 68];
  __shared__ float Lsm[3][32];
  const int bh = blockIdx.x, qi = blockIdx.y;
  const int g = (qi & ~7) | (((qi >> 3) & 1) ? (7 - (qi & 7)) : (qi & 7));
  const int tid = threadIdx.x, p = tid >> 6, lane = tid & 63;
  const int lo5 = lane & 31, hi = lane >> 5;
  const int nt = (g >> 1) + 1;
  const int qq = nt >> 2, rem = nt & 3;
  const int cnt = qq + (p < rem ? 1 : 0);
  const int t0 = p * qq + (p < rem ? p : rem);
  const int bb = bh >> 4, h = bh & 15;

  const u16* Qb = Qf + (size_t)bh * 131072 + (size_t)g * 2048 + lane * 8;
  const u16* Kb = Kf + (size_t)bh * 131072 + lane * 8;
  const u16* Vb = Vf + (size_t)bh * 131072 + hi * 512 + lo5 * 8;

  bf16x8 qf[4];
#pragma unroll
  for (int d = 0; d < 4; ++d) qf[d] = *(const bf16x8*)(Qb + d * 512);

  f32x16 O0, O1;
#pragma unroll
  for (int r = 0; r < 16; ++r) { O0[r] = 0.f; O1[r] = 0.f; }
  float l_run = 0.f;

  bf16x8 kA0[4], kB0[4], kA1[4], kB1[4];

  auto LOADK = [&](int t, bf16x8 (&kA)[4], bf16x8 (&kB)[4]) {
    const u16* kt = Kb + (size_t)t * 4096;
#pragma unroll
    for (int d = 0; d < 4; ++d) {
      kA[d] = *(const bf16x8*)(kt + d * 512);
      kB[d] = *(const bf16x8*)(kt + 2048 + d * 512);
    }
  };

  auto COMPUTE = [&](int t, bf16x8 (&kA)[4], bf16x8 (&kB)[4]) {
    f32x16 s0, s1;
#pragma unroll
    for (int r = 0; r < 16; ++r) { s0[r] = 0.f; s1[r] = 0.f; }
    __builtin_amdgcn_s_setprio(1);
#pragma unroll
    for (int d = 0; d < 4; ++d) {
      s0 = __builtin_amdgcn_mfma_f32_32x32x16_bf16(kA[d], qf[d], s0, 0, 0, 0);
      s1 = __builtin_amdgcn_mfma_f32_32x32x16_bf16(kB[d], qf[d], s1, 0, 0, 0);
    }
    __builtin_amdgcn_s_setprio(0);

    const u16* vt = Vb + (size_t)t * 4096;
    bf16x8 vA[4], vB[4];
#pragma unroll
    for (int ks = 0; ks < 4; ++ks) {
      vA[ks] = *(const bf16x8*)(vt + ks * 1024);
      vB[ks] = *(const bf16x8*)(vt + ks * 1024 + 256);
    }

    if (t == nt - 1) {
#pragma unroll
      for (int r = 0; r < 16; ++r) {
        int kl = (r & 3) + 8 * (r >> 2) + 4 * hi;
        if (g & 1) {
          if (kl > lo5) s1[r] = -1e30f;
        } else {
          if (kl > lo5) s0[r] = -1e30f;
          s1[r] = -1e30f;
        }
      }
    }

    float sm[16];
#pragma unroll
    for (int r = 0; r < 16; ++r) {
      float p0 = exp2f(s0[r]); s0[r] = p0;
      float p1 = exp2f(s1[r]); s1[r] = p1;
      sm[r] = p0 + p1;
    }
#pragma unroll
    for (int d = 8; d; d >>= 1)
#pragma unroll
      for (int r = 0; r < d; ++r) sm[r] += sm[r + d];
    l_run += sm[0];

    uint32_t W0[8], W1[8];
#pragma unroll
    for (int i = 0; i < 8; ++i) {
      W0[i] = cvtpk(s0[2 * i], s0[2 * i + 1]);
      W1[i] = cvtpk(s1[2 * i], s1[2 * i + 1]);
    }
    __builtin_amdgcn_s_setprio(1);
#pragma unroll
    for (int ks = 0; ks < 4; ++ks) {
      uint32_t a, d2, c2, e2;
      if (ks == 0)      { a = W0[0]; d2 = W0[1]; c2 = W0[2]; e2 = W0[3]; }
      else if (ks == 1) { a = W0[4]; d2 = W0[5]; c2 = W0[6]; e2 = W0[7]; }
      else if (ks == 2) { a = W1[0]; d2 = W1[1]; c2 = W1[2]; e2 = W1[3]; }
      else              { a = W1[4]; d2 = W1[5]; c2 = W1[6]; e2 = W1[7]; }
      plswap(a, c2);
      plswap(d2, e2);
      union { uint32_t u[4]; bf16x8 v; } f;
      f.u[0] = a; f.u[1] = d2; f.u[2] = c2; f.u[3] = e2;
      O0 = __builtin_amdgcn_mfma_f32_32x32x16_bf16(vA[ks], f.v, O0, 0, 0, 0);
      O1 = __builtin_amdgcn_mfma_f32_32x32x16_bf16(vB[ks], f.v, O1, 0, 0, 0);
    }
    __builtin_amdgcn_s_setprio(0);
  };

  if (cnt > 0) {
    LOADK(t0, kA0, kB0);
    int i = 0;
    for (;;) {
      if (i + 1 < cnt) LOADK(t0 + i + 1, kA1, kB1);
      COMPUTE(t0 + i, kA0, kB0);
      if (++i >= cnt) break;
      if (i + 1 < cnt) LOADK(t0 + i + 1, kA0, kB0);
      COMPUTE(t0 + i, kA1, kB1);
      if (++i >= cnt) break;
    }
  }

  l_run += __shfl_xor(l_run, 32);

  if (p != 0) {
    u16* om = Omb[p - 1] + (size_t)lo5 * 68;
#pragma unroll
    for (int gg = 0; gg < 4; ++gg) {
      int off = 8 * gg + 4 * hi;
      u16x4 w0, w1;
#pragma unroll
      for (int j = 0; j < 4; ++j) { w0[j] = f2bf(O0[4 * gg + j]); w1[j] = f2bf(O1[4 * gg + j]); }
      *(u16x4*)(om + off) = w0;
      *(u16x4*)(om + 32 + off) = w1;
    }
    if (hi == 0) Lsm[p - 1][lo5] = l_run;
  }
  __syncthreads();
  if (p == 0) {
    float invl = 1.0f / (l_run + Lsm[0][lo5] + Lsm[1][lo5] + Lsm[2][lo5]);
    const u16* om1 = Omb[0] + (size_t)lo5 * 68;
    const u16* om2 = Omb[1] + (size_t)lo5 * 68;
    const u16* om3 = Omb[2] + (size_t)lo5 * 68;
    const int tq = 32 * g + lo5;
    size_t rowb = ((size_t)(bb * 2048 + tq)) * 1024 + h * 64;
#pragma unroll
    for (int gg = 0; gg < 4; ++gg) {
      int off = 8 * gg + 4 * hi;
      u16x4 q1 = *(const u16x4*)(om1 + off), q2 = *(const u16x4*)(om2 + off), q3 = *(const u16x4*)(om3 + off);
      u16x4 pk;
#pragma unroll
      for (int j = 0; j < 4; ++j)
        pk[j] = f2bf((O0[4 * gg + j] + bf2f(q1[j]) + bf2f(q2[j]) + bf2f(q3[j])) * invl);
      *(u16x4*)(ctx + rowb + off) = pk;
      u16x4 r1 = *(const u16x4*)(om1 + 32 + off), r2 = *(const u16x4*)(om2 + 32 + off), r3 = *(const u16x4*)(om3 + 32 + off);
#pragma unroll
      for (int j = 0; j < 4; ++j)
        pk[j] = f2bf((O1[4 * gg + j] + bf2f(r1[j]) + bf2f(r2[j]) + bf2f(r3[j])) * invl);
      *(u16x4*)(ctx + rowb + 32 + off) = pk;
    }
  }
}

// ---------- output projection (8-wave): out = ctx @ w_o (f32 out) ----------
__global__ __launch_bounds__(512, 4) void out_gemm_kernel(const u16* __restrict__ ctxb,
                                                          const u16* __restrict__ Wot,
                                                          float* __restrict__ out) {
  __shared__ u16 As[2][4096];
  __shared__ u16 Bs[2][4096];
  const int m0 = blockIdx.x * 128, n0 = blockIdx.y * 128;
  f32x4 acc[4][2];
  const f32x4 z4 = {0.f, 0.f, 0.f, 0.f};
#pragma unroll
  for (int i = 0; i < 4; ++i)
#pragma unroll
    for (int j = 0; j < 2; ++j) acc[i][j] = z4;
  gemm_mainloop8(ctxb, Wot, m0, n0, As, Bs, acc);
  const int tid = threadIdx.x, w = tid >> 6, lane = tid & 63, lo = lane & 15, hi = lane >> 4;
  const int colb = n0 + ((w >> 1) & 1) * 64 + (w & 1) * 16;
#pragma unroll
  for (int mi = 0; mi < 4; ++mi)
#pragma unroll
    for (int r = 0; r < 4; ++r) {
      int tg = m0 + (w >> 2) * 64 + mi * 16 + hi * 4 + r;
      out[(size_t)tg * 1024 + colb + lo] = acc[mi][0][r];
      out[(size_t)tg * 1024 + colb + 32 + lo] = acc[mi][1][r];
    }
}

// ---------- launch ----------
extern "C" void kernel_launch(void* const* d_in, const int* in_sizes, int n_in,
                              void* d_out, int out_size, void* d_ws, size_t ws_size,
                              hipStream_t stream) {
  (void)in_sizes; (void)n_in; (void)out_size; (void)ws_size;
  const float* x  = (const float*)d_in[0];
  const float* wq = (const float*)d_in[1];
  const float* wk = (const float*)d_in[2];
  const float* wv = (const float*)d_in[3];
  const float* wo = (const float*)d_in[4];
  char* ws = (char*)d_ws;
  u16* xb   = (u16*)(ws + (size_t)0);
  u16* Wqt  = (u16*)(ws + ((size_t)8  << 20));   // Wqt/Wkt/Wvt contiguous: 3072x1024
  u16* Wkt  = (u16*)(ws + ((size_t)10 << 20));
  u16* Wvt  = (u16*)(ws + ((size_t)12 << 20));
  u16* Wot  = (u16*)(ws + ((size_t)14 << 20));
  u16* Qf   = (u16*)(ws + ((size_t)16 << 20));
  u16* Kf   = (u16*)(ws + ((size_t)24 << 20));
  u16* Vf   = (u16*)(ws + ((size_t)32 << 20));
  u16* ctxb = (u16*)(ws + ((size_t)40 << 20));

  prep_kernel<<<5120, 256, 0, stream>>>(x, wq, wk, wv, wo, xb, Wqt, Wkt, Wvt, Wot);
  qkv_gemm_kernel<<<dim3(32, 24), 512, 0, stream>>>(xb, Wqt, Qf, Kf, Vf);
  attn_kernel<<<dim3(32, 64), 256, 0, stream>>>(Qf, Kf, Vf, ctxb);
  out_gemm_kernel<<<dim3(32, 8), 512, 0, stream>>>(ctxb, Wot, (float*)d_out);
}

// Round 17
// 105.347 us; speedup vs baseline: 1.7293x; 1.0077x over previous
//
#include <hip/hip_runtime.h>
#include <hip/hip_bf16.h>
#include <cstdint>

using u16 = unsigned short;
typedef short bf16x8 __attribute__((ext_vector_type(8)));
typedef float f32x4 __attribute__((ext_vector_type(4)));
typedef float f32x16 __attribute__((ext_vector_type(16)));
typedef u16 u16x4 __attribute__((ext_vector_type(4)));
typedef u16 u16x8 __attribute__((ext_vector_type(8)));

// ---------- helpers ----------
__device__ __forceinline__ u16 f2bf(float f) {
  union { float f; uint32_t u; } v; v.f = f;
  uint32_t r = (v.u + 0x7fffu + ((v.u >> 16) & 1u)) >> 16;  // RNE
  return (u16)r;
}

__device__ __forceinline__ float bf2f(u16 u) {
  union { uint32_t u; float f; } v; v.u = (uint32_t)u << 16; return v.f;
}

__device__ __forceinline__ void async16(const void* g, void* l) {
  __builtin_amdgcn_global_load_lds(
      (const __attribute__((address_space(1))) uint32_t*)g,
      (__attribute__((address_space(3))) uint32_t*)l, 16, 0, 0);
}

__device__ __forceinline__ uint32_t cvtpk(float a, float b) {
  uint32_t r;
  asm("v_cvt_pk_bf16_f32 %0, %1, %2" : "=v"(r) : "v"(a), "v"(b));
  return r;
}

// swap upper 32 lanes of a with lower 32 lanes of b (validated in PV path since r2)
__device__ __forceinline__ void plswap(uint32_t& a, uint32_t& b) {
  asm volatile("v_permlane32_swap_b32 %0, %1" : "+v"(a), "+v"(b));
}

// ---------- fused prep: cvt x (blocks 0..4095) + 4x weight transpose (4096..5119) ----------
__global__ __launch_bounds__(256) void prep_kernel(
    const float* __restrict__ x, const float* __restrict__ wq, const float* __restrict__ wk,
    const float* __restrict__ wv, const float* __restrict__ wo,
    u16* __restrict__ xb, u16* __restrict__ Wqt, u16* __restrict__ Wkt,
    u16* __restrict__ Wvt, u16* __restrict__ Wot) {
  __shared__ float tile[64][65];
  const int tid = threadIdx.x;
  const int bid = blockIdx.x;
  if (bid < 4096) {
    int i = (bid * 256 + tid) * 4;
    float4 v = *(const float4*)(x + i);
    u16x4 o;
    o[0] = f2bf(v.x); o[1] = f2bf(v.y); o[2] = f2bf(v.z); o[3] = f2bf(v.w);
    *(u16x4*)(xb + i) = o;
    return;
  }
  const int id = bid - 4096;
  const int wsel = id >> 8, sub = id & 255;
  const float* W = (wsel == 0) ? wq : (wsel == 1) ? wk : (wsel == 2) ? wv : wo;
  u16* Wt = (wsel == 0) ? Wqt : (wsel == 1) ? Wkt : (wsel == 2) ? Wvt : Wot;
  const int k0 = (sub & 15) * 64, n0 = (sub >> 4) * 64;
#pragma unroll
  for (int i = 0; i < 4; ++i) {
    int c = i * 256 + tid;
    int r = c >> 4, c4 = c & 15;
    float4 v = *(const float4*)(W + (size_t)(k0 + r) * 1024 + n0 + c4 * 4);
    tile[r][c4 * 4 + 0] = v.x; tile[r][c4 * 4 + 1] = v.y;
    tile[r][c4 * 4 + 2] = v.z; tile[r][c4 * 4 + 3] = v.w;
  }
  __syncthreads();
#pragma unroll
  for (int i = 0; i < 2; ++i) {
    int c = i * 256 + tid;
    int n = c >> 3, kc = c & 7;
    u16x8 o;
#pragma unroll
    for (int j = 0; j < 8; ++j) o[j] = f2bf(tile[kc * 8 + j][n]);
    *(u16x8*)(Wt + (size_t)(n0 + n) * 1024 + k0 + kc * 8) = o;
  }
}

// ---------- 8-wave GEMM mainloop: C(128x128) = A(128xK) * Bt(128xK)^T, K=1024 ----------
__device__ __forceinline__ void stage8(const u16* A, const u16* Bt, int m0, int n0, int kt,
                                       u16* As, u16* Bs, int tid) {
  int row = tid >> 2, cc = tid & 3;
  int koff = kt * 32 + ((cc ^ (row & 3)) << 3);
  async16(A + (size_t)(m0 + row) * 1024 + koff, As + (size_t)tid * 8);
  async16(Bt + (size_t)(n0 + row) * 1024 + koff, Bs + (size_t)tid * 8);
}

__device__ __forceinline__ void gemm_mainloop8(const u16* A, const u16* Bt, int m0, int n0,
                                               u16 (*As)[4096], u16 (*Bs)[4096], f32x4 acc[4][2]) {
  const int tid = threadIdx.x, w = tid >> 6, lane = tid & 63, lo = lane & 15, hi = lane >> 4;
  const int mb = (w >> 2) * 64;
  const int cb = ((w >> 1) & 1) * 64 + (w & 1) * 16;
  stage8(A, Bt, m0, n0, 0, As[0], Bs[0], tid);
  __syncthreads();
  for (int kt = 0; kt < 32; ++kt) {
    int cur = kt & 1;
    if (kt + 1 < 32) stage8(A, Bt, m0, n0, kt + 1, As[cur ^ 1], Bs[cur ^ 1], tid);
    const int sw = (hi ^ (lo & 3)) << 3;
    bf16x8 af[4], bfr[2];
#pragma unroll
    for (int i = 0; i < 4; ++i) af[i] = *(const bf16x8*)(As[cur] + (mb + i * 16 + lo) * 32 + sw);
#pragma unroll
    for (int j = 0; j < 2; ++j) bfr[j] = *(const bf16x8*)(Bs[cur] + (cb + j * 32 + lo) * 32 + sw);
#pragma unroll
    for (int i = 0; i < 4; ++i)
#pragma unroll
      for (int j = 0; j < 2; ++j)
        acc[i][j] = __builtin_amdgcn_mfma_f32_16x16x32_bf16(af[i], bfr[j], acc[i][j], 0, 0, 0);
    __syncthreads();
  }
}

// ---------- FUSED QKV projection + RoPE + scatter (8-wave) ----------
__global__ __launch_bounds__(512, 4) void qkv_gemm_kernel(
    const u16* __restrict__ xb, const u16* __restrict__ Wcat,
    u16* __restrict__ Qf, u16* __restrict__ Kf, u16* __restrict__ Vf) {
  __shared__ u16 As[2][4096];
  __shared__ u16 Bs[2][4096];
  const int m0 = blockIdx.x * 128, n0 = blockIdx.y * 128;
  const int mode = n0 >> 10, nloc = n0 & 1023;
  f32x4 acc[4][2];
  const f32x4 z4 = {0.f, 0.f, 0.f, 0.f};
#pragma unroll
  for (int i = 0; i < 4; ++i)
#pragma unroll
    for (int j = 0; j < 2; ++j) acc[i][j] = z4;
  gemm_mainloop8(xb, Wcat, m0, n0, As, Bs, acc);

  const int tid = threadIdx.x, w = tid >> 6, lane = tid & 63, lo = lane & 15, hi = lane >> 4;
  const int c1 = (w >> 1) & 1, c2 = w & 1;
  const int h = (nloc >> 6) + c1;
  const int mrow0 = m0 + (w >> 2) * 64;
  if (mode < 2) {
    u16* Out = (mode == 0) ? Qf : Kf;
    const float qscale = (mode == 0) ? 0.18033688011112042f : 1.0f;
    const float invf = exp2f(-(float)(c2 * 16 + lo) * 0.41524101186092034f);
    const int lnoff = (lo >> 3) * 256 + (lo & 7) + c2 * 512;
#pragma unroll
    for (int mi = 0; mi < 4; ++mi) {
#pragma unroll
      for (int r = 0; r < 4; ++r) {
        int tg = mrow0 + mi * 16 + hi * 4 + r;
        int b = tg >> 11, tp = tg & 2047;
        float cs, sn;
        __sincosf((float)tp * invf, &sn, &cs);
        size_t obase = (size_t)((b * 16 + h) * 64 + (tp >> 5)) * 2048 + (size_t)(tp & 31) * 8 + lnoff;
        float v0 = acc[mi][0][r], v1 = acc[mi][1][r];
        Out[obase]        = f2bf((v0 * cs - v1 * sn) * qscale);
        Out[obase + 1024] = f2bf((v1 * cs + v0 * sn) * qscale);
      }
    }
  } else {
#pragma unroll
    for (int mi = 0; mi < 4; ++mi) {
      int tg0 = mrow0 + mi * 16 + hi * 4;
      int b = tg0 >> 11, tp0 = tg0 & 2047;
#pragma unroll
      for (int j = 0; j < 2; ++j) {
        int d = c2 * 16 + j * 32 + lo;
        u16x4 pk;
#pragma unroll
        for (int r = 0; r < 4; ++r) pk[r] = f2bf(acc[mi][j][r]);
        *(u16x4*)(Vf + ((size_t)((b * 16 + h) * 256 + (tp0 >> 3)) * 64 + d) * 8 + (tp0 & 7)) = pk;
      }
    }
  }
}

// ---------- flash attention: 4 independent waves, FIXED-m softmax (r14 config) ----------
// grid (bh=32, qi=64), 256 thr. Wave p takes a quarter of g's 64-key tiles.
// Double K named-set prefetch, (256,2) cap — measured 42us / VGPR 108 / no spill.
// LPT dispatch: qr = 63-qi reverses launch order so the LONGEST blocks (g=63..56,
// 8 tiles/wave) start first and short blocks backfill — r16 profile showed 15%
// time-avg occupancy from an anti-LPT tail (shortest-first). Reversal flips
// residue class r -> 7-r; all classes remain exactly balanced (132 tiles each).
__global__ __launch_bounds__(256, 2) void attn_kernel(const u16* __restrict__ Qf, const u16* __restrict__ Kf,
                                                      const u16* __restrict__ Vf, u16* __restrict__ ctx) {
  __shared__ u16 Omb[3][32 * 68];
  __shared__ float Lsm[3][32];
  const int bh = blockIdx.x, qi = blockIdx.y;
  const int qr = 63 - qi;
  const int g = (qr & ~7) | (((qr >> 3) & 1) ? (7 - (qr & 7)) : (qr & 7));
  const int tid = threadIdx.x, p = tid >> 6, lane = tid & 63;
  const int lo5 = lane & 31, hi = lane >> 5;
  const int nt = (g >> 1) + 1;
  const int qq = nt >> 2, rem = nt & 3;
  const int cnt = qq + (p < rem ? 1 : 0);
  const int t0 = p * qq + (p < rem ? p : rem);
  const int bb = bh >> 4, h = bh & 15;

  const u16* Qb = Qf + (size_t)bh * 131072 + (size_t)g * 2048 + lane * 8;
  const u16* Kb = Kf + (size_t)bh * 131072 + lane * 8;
  const u16* Vb = Vf + (size_t)bh * 131072 + hi * 512 + lo5 * 8;

  bf16x8 qf[4];
#pragma unroll
  for (int d = 0; d < 4; ++d) qf[d] = *(const bf16x8*)(Qb + d * 512);

  f32x16 O0, O1;
#pragma unroll
  for (int r = 0; r < 16; ++r) { O0[r] = 0.f; O1[r] = 0.f; }
  float l_run = 0.f;

  bf16x8 kA0[4], kB0[4], kA1[4], kB1[4];

  auto LOADK = [&](int t, bf16x8 (&kA)[4], bf16x8 (&kB)[4]) {
    const u16* kt = Kb + (size_t)t * 4096;
#pragma unroll
    for (int d = 0; d < 4; ++d) {
      kA[d] = *(const bf16x8*)(kt + d * 512);
      kB[d] = *(const bf16x8*)(kt + 2048 + d * 512);
    }
  };

  auto COMPUTE = [&](int t, bf16x8 (&kA)[4], bf16x8 (&kB)[4]) {
    f32x16 s0, s1;
#pragma unroll
    for (int r = 0; r < 16; ++r) { s0[r] = 0.f; s1[r] = 0.f; }
    __builtin_amdgcn_s_setprio(1);
#pragma unroll
    for (int d = 0; d < 4; ++d) {
      s0 = __builtin_amdgcn_mfma_f32_32x32x16_bf16(kA[d], qf[d], s0, 0, 0, 0);
      s1 = __builtin_amdgcn_mfma_f32_32x32x16_bf16(kB[d], qf[d], s1, 0, 0, 0);
    }
    __builtin_amdgcn_s_setprio(0);

    const u16* vt = Vb + (size_t)t * 4096;
    bf16x8 vA[4], vB[4];
#pragma unroll
    for (int ks = 0; ks < 4; ++ks) {
      vA[ks] = *(const bf16x8*)(vt + ks * 1024);
      vB[ks] = *(const bf16x8*)(vt + ks * 1024 + 256);
    }

    if (t == nt - 1) {
#pragma unroll
      for (int r = 0; r < 16; ++r) {
        int kl = (r & 3) + 8 * (r >> 2) + 4 * hi;
        if (g & 1) {
          if (kl > lo5) s1[r] = -1e30f;
        } else {
          if (kl > lo5) s0[r] = -1e30f;
          s1[r] = -1e30f;
        }
      }
    }

    float sm[16];
#pragma unroll
    for (int r = 0; r < 16; ++r) {
      float p0 = exp2f(s0[r]); s0[r] = p0;
      float p1 = exp2f(s1[r]); s1[r] = p1;
      sm[r] = p0 + p1;
    }
#pragma unroll
    for (int d = 8; d; d >>= 1)
#pragma unroll
      for (int r = 0; r < d; ++r) sm[r] += sm[r + d];
    l_run += sm[0];

    uint32_t W0[8], W1[8];
#pragma unroll
    for (int i = 0; i < 8; ++i) {
      W0[i] = cvtpk(s0[2 * i], s0[2 * i + 1]);
      W1[i] = cvtpk(s1[2 * i], s1[2 * i + 1]);
    }
    __builtin_amdgcn_s_setprio(1);
#pragma unroll
    for (int ks = 0; ks < 4; ++ks) {
      uint32_t a, d2, c2, e2;
      if (ks == 0)      { a = W0[0]; d2 = W0[1]; c2 = W0[2]; e2 = W0[3]; }
      else if (ks == 1) { a = W0[4]; d2 = W0[5]; c2 = W0[6]; e2 = W0[7]; }
      else if (ks == 2) { a = W1[0]; d2 = W1[1]; c2 = W1[2]; e2 = W1[3]; }
      else              { a = W1[4]; d2 = W1[5]; c2 = W1[6]; e2 = W1[7]; }
      plswap(a, c2);
      plswap(d2, e2);
      union { uint32_t u[4]; bf16x8 v; } f;
      f.u[0] = a; f.u[1] = d2; f.u[2] = c2; f.u[3] = e2;
      O0 = __builtin_amdgcn_mfma_f32_32x32x16_bf16(vA[ks], f.v, O0, 0, 0, 0);
      O1 = __builtin_amdgcn_mfma_f32_32x32x16_bf16(vB[ks], f.v, O1, 0, 0, 0);
    }
    __builtin_amdgcn_s_setprio(0);
  };

  if (cnt > 0) {
    LOADK(t0, kA0, kB0);
    int i = 0;
    for (;;) {
      if (i + 1 < cnt) LOADK(t0 + i + 1, kA1, kB1);
      COMPUTE(t0 + i, kA0, kB0);
      if (++i >= cnt) break;
      if (i + 1 < cnt) LOADK(t0 + i + 1, kA0, kB0);
      COMPUTE(t0 + i, kA1, kB1);
      if (++i >= cnt) break;
    }
  }

  l_run += __shfl_xor(l_run, 32);

  if (p != 0) {
    u16* om = Omb[p - 1] + (size_t)lo5 * 68;
#pragma unroll
    for (int gg = 0; gg < 4; ++gg) {
      int off = 8 * gg + 4 * hi;
      u16x4 w0, w1;
#pragma unroll
      for (int j = 0; j < 4; ++j) { w0[j] = f2bf(O0[4 * gg + j]); w1[j] = f2bf(O1[4 * gg + j]); }
      *(u16x4*)(om + off) = w0;
      *(u16x4*)(om + 32 + off) = w1;
    }
    if (hi == 0) Lsm[p - 1][lo5] = l_run;
  }
  __syncthreads();
  if (p == 0) {
    float invl = 1.0f / (l_run + Lsm[0][lo5] + Lsm[1][lo5] + Lsm[2][lo5]);
    const u16* om1 = Omb[0] + (size_t)lo5 * 68;
    const u16* om2 = Omb[1] + (size_t)lo5 * 68;
    const u16* om3 = Omb[2] + (size_t)lo5 * 68;
    const int tq = 32 * g + lo5;
    size_t rowb = ((size_t)(bb * 2048 + tq)) * 1024 + h * 64;
#pragma unroll
    for (int gg = 0; gg < 4; ++gg) {
      int off = 8 * gg + 4 * hi;
      u16x4 q1 = *(const u16x4*)(om1 + off), q2 = *(const u16x4*)(om2 + off), q3 = *(const u16x4*)(om3 + off);
      u16x4 pk;
#pragma unroll
      for (int j = 0; j < 4; ++j)
        pk[j] = f2bf((O0[4 * gg + j] + bf2f(q1[j]) + bf2f(q2[j]) + bf2f(q3[j])) * invl);
      *(u16x4*)(ctx + rowb + off) = pk;
      u16x4 r1 = *(const u16x4*)(om1 + 32 + off), r2 = *(const u16x4*)(om2 + 32 + off), r3 = *(const u16x4*)(om3 + 32 + off);
#pragma unroll
      for (int j = 0; j < 4; ++j)
        pk[j] = f2bf((O1[4 * gg + j] + bf2f(r1[j]) + bf2f(r2[j]) + bf2f(r3[j])) * invl);
      *(u16x4*)(ctx + rowb + 32 + off) = pk;
    }
  }
}

// ---------- output projection (8-wave): out = ctx @ w_o (f32 out) ----------
__global__ __launch_bounds__(512, 4) void out_gemm_kernel(const u16* __restrict__ ctxb,
                                                          const u16* __restrict__ Wot,
                                                          float* __restrict__ out) {
  __shared__ u16 As[2][4096];
  __shared__ u16 Bs[2][4096];
  const int m0 = blockIdx.x * 128, n0 = blockIdx.y * 128;
  f32x4 acc[4][2];
  const f32x4 z4 = {0.f, 0.f, 0.f, 0.f};
#pragma unroll
  for (int i = 0; i < 4; ++i)
#pragma unroll
    for (int j = 0; j < 2; ++j) acc[i][j] = z4;
  gemm_mainloop8(ctxb, Wot, m0, n0, As, Bs, acc);
  const int tid = threadIdx.x, w = tid >> 6, lane = tid & 63, lo = lane & 15, hi = lane >> 4;
  const int colb = n0 + ((w >> 1) & 1) * 64 + (w & 1) * 16;
#pragma unroll
  for (int mi = 0; mi < 4; ++mi)
#pragma unroll
    for (int r = 0; r < 4; ++r) {
      int tg = m0 + (w >> 2) * 64 + mi * 16 + hi * 4 + r;
      out[(size_t)tg * 1024 + colb + lo] = acc[mi][0][r];
      out[(size_t)tg * 1024 + colb + 32 + lo] = acc[mi][1][r];
    }
}

// ---------- launch ----------
extern "C" void kernel_launch(void* const* d_in, const int* in_sizes, int n_in,
                              void* d_out, int out_size, void* d_ws, size_t ws_size,
                              hipStream_t stream) {
  (void)in_sizes; (void)n_in; (void)out_size; (void)ws_size;
  const float* x  = (const float*)d_in[0];
  const float* wq = (const float*)d_in[1];
  const float* wk = (const float*)d_in[2];
  const float* wv = (const float*)d_in[3];
  const float* wo = (const float*)d_in[4];
  char* ws = (char*)d_ws;
  u16* xb   = (u16*)(ws + (size_t)0);
  u16* Wqt  = (u16*)(ws + ((size_t)8  << 20));   // Wqt/Wkt/Wvt contiguous: 3072x1024
  u16* Wkt  = (u16*)(ws + ((size_t)10 << 20));
  u16* Wvt  = (u16*)(ws + ((size_t)12 << 20));
  u16* Wot  = (u16*)(ws + ((size_t)14 << 20));
  u16* Qf   = (u16*)(ws + ((size_t)16 << 20));
  u16* Kf   = (u16*)(ws + ((size_t)24 << 20));
  u16* Vf   = (u16*)(ws + ((size_t)32 << 20));
  u16* ctxb = (u16*)(ws + ((size_t)40 << 20));

  prep_kernel<<<5120, 256, 0, stream>>>(x, wq, wk, wv, wo, xb, Wqt, Wkt, Wvt, Wot);
  qkv_gemm_kernel<<<dim3(32, 24), 512, 0, stream>>>(xb, Wqt, Qf, Kf, Vf);
  attn_kernel<<<dim3(32, 64), 256, 0, stream>>>(Qf, Kf, Vf, ctxb);
  out_gemm_kernel<<<dim3(32, 8), 512, 0, stream>>>(ctxb, Wot, (float*)d_out);
}

// Round 18
// 104.974 us; speedup vs baseline: 1.7354x; 1.0036x over previous
//
#include <hip/hip_runtime.h>
#include <hip/hip_bf16.h>
#include <cstdint>

using u16 = unsigned short;
typedef short bf16x8 __attribute__((ext_vector_type(8)));
typedef float f32x4 __attribute__((ext_vector_type(4)));
typedef float f32x16 __attribute__((ext_vector_type(16)));
typedef u16 u16x4 __attribute__((ext_vector_type(4)));
typedef u16 u16x8 __attribute__((ext_vector_type(8)));

// ---------- helpers ----------
__device__ __forceinline__ u16 f2bf(float f) {
  union { float f; uint32_t u; } v; v.f = f;
  uint32_t r = (v.u + 0x7fffu + ((v.u >> 16) & 1u)) >> 16;  // RNE
  return (u16)r;
}

__device__ __forceinline__ float bf2f(u16 u) {
  union { uint32_t u; float f; } v; v.u = (uint32_t)u << 16; return v.f;
}

__device__ __forceinline__ void async16(const void* g, void* l) {
  __builtin_amdgcn_global_load_lds(
      (const __attribute__((address_space(1))) uint32_t*)g,
      (__attribute__((address_space(3))) uint32_t*)l, 16, 0, 0);
}

__device__ __forceinline__ uint32_t cvtpk(float a, float b) {
  uint32_t r;
  asm("v_cvt_pk_bf16_f32 %0, %1, %2" : "=v"(r) : "v"(a), "v"(b));
  return r;
}

// swap upper 32 lanes of a with lower 32 lanes of b (validated in PV path since r2)
__device__ __forceinline__ void plswap(uint32_t& a, uint32_t& b) {
  asm volatile("v_permlane32_swap_b32 %0, %1" : "+v"(a), "+v"(b));
}

// ---------- fused prep: cvt x (blocks 0..4095) + 4x weight transpose (4096..5119) ----------
__global__ __launch_bounds__(256) void prep_kernel(
    const float* __restrict__ x, const float* __restrict__ wq, const float* __restrict__ wk,
    const float* __restrict__ wv, const float* __restrict__ wo,
    u16* __restrict__ xb, u16* __restrict__ Wqt, u16* __restrict__ Wkt,
    u16* __restrict__ Wvt, u16* __restrict__ Wot) {
  __shared__ float tile[64][65];
  const int tid = threadIdx.x;
  const int bid = blockIdx.x;
  if (bid < 4096) {
    int i = (bid * 256 + tid) * 4;
    float4 v = *(const float4*)(x + i);
    u16x4 o;
    o[0] = f2bf(v.x); o[1] = f2bf(v.y); o[2] = f2bf(v.z); o[3] = f2bf(v.w);
    *(u16x4*)(xb + i) = o;
    return;
  }
  const int id = bid - 4096;
  const int wsel = id >> 8, sub = id & 255;
  const float* W = (wsel == 0) ? wq : (wsel == 1) ? wk : (wsel == 2) ? wv : wo;
  u16* Wt = (wsel == 0) ? Wqt : (wsel == 1) ? Wkt : (wsel == 2) ? Wvt : Wot;
  const int k0 = (sub & 15) * 64, n0 = (sub >> 4) * 64;
#pragma unroll
  for (int i = 0; i < 4; ++i) {
    int c = i * 256 + tid;
    int r = c >> 4, c4 = c & 15;
    float4 v = *(const float4*)(W + (size_t)(k0 + r) * 1024 + n0 + c4 * 4);
    tile[r][c4 * 4 + 0] = v.x; tile[r][c4 * 4 + 1] = v.y;
    tile[r][c4 * 4 + 2] = v.z; tile[r][c4 * 4 + 3] = v.w;
  }
  __syncthreads();
#pragma unroll
  for (int i = 0; i < 2; ++i) {
    int c = i * 256 + tid;
    int n = c >> 3, kc = c & 7;
    u16x8 o;
#pragma unroll
    for (int j = 0; j < 8; ++j) o[j] = f2bf(tile[kc * 8 + j][n]);
    *(u16x8*)(Wt + (size_t)(n0 + n) * 1024 + k0 + kc * 8) = o;
  }
}

// ---------- 8-wave GEMM mainloop: C(128x128) = A(128xK) * Bt(128xK)^T, K=1024 ----------
__device__ __forceinline__ void stage8(const u16* A, const u16* Bt, int m0, int n0, int kt,
                                       u16* As, u16* Bs, int tid) {
  int row = tid >> 2, cc = tid & 3;
  int koff = kt * 32 + ((cc ^ (row & 3)) << 3);
  async16(A + (size_t)(m0 + row) * 1024 + koff, As + (size_t)tid * 8);
  async16(Bt + (size_t)(n0 + row) * 1024 + koff, Bs + (size_t)tid * 8);
}

__device__ __forceinline__ void gemm_mainloop8(const u16* A, const u16* Bt, int m0, int n0,
                                               u16 (*As)[4096], u16 (*Bs)[4096], f32x4 acc[4][2]) {
  const int tid = threadIdx.x, w = tid >> 6, lane = tid & 63, lo = lane & 15, hi = lane >> 4;
  const int mb = (w >> 2) * 64;
  const int cb = ((w >> 1) & 1) * 64 + (w & 1) * 16;
  stage8(A, Bt, m0, n0, 0, As[0], Bs[0], tid);
  __syncthreads();
  for (int kt = 0; kt < 32; ++kt) {
    int cur = kt & 1;
    if (kt + 1 < 32) stage8(A, Bt, m0, n0, kt + 1, As[cur ^ 1], Bs[cur ^ 1], tid);
    const int sw = (hi ^ (lo & 3)) << 3;
    bf16x8 af[4], bfr[2];
#pragma unroll
    for (int i = 0; i < 4; ++i) af[i] = *(const bf16x8*)(As[cur] + (mb + i * 16 + lo) * 32 + sw);
#pragma unroll
    for (int j = 0; j < 2; ++j) bfr[j] = *(const bf16x8*)(Bs[cur] + (cb + j * 32 + lo) * 32 + sw);
#pragma unroll
    for (int i = 0; i < 4; ++i)
#pragma unroll
      for (int j = 0; j < 2; ++j)
        acc[i][j] = __builtin_amdgcn_mfma_f32_16x16x32_bf16(af[i], bfr[j], acc[i][j], 0, 0, 0);
    __syncthreads();
  }
}

// ---------- FUSED QKV projection + RoPE + scatter (8-wave) ----------
__global__ __launch_bounds__(512, 4) void qkv_gemm_kernel(
    const u16* __restrict__ xb, const u16* __restrict__ Wcat,
    u16* __restrict__ Qf, u16* __restrict__ Kf, u16* __restrict__ Vf) {
  __shared__ u16 As[2][4096];
  __shared__ u16 Bs[2][4096];
  const int m0 = blockIdx.x * 128, n0 = blockIdx.y * 128;
  const int mode = n0 >> 10, nloc = n0 & 1023;
  f32x4 acc[4][2];
  const f32x4 z4 = {0.f, 0.f, 0.f, 0.f};
#pragma unroll
  for (int i = 0; i < 4; ++i)
#pragma unroll
    for (int j = 0; j < 2; ++j) acc[i][j] = z4;
  gemm_mainloop8(xb, Wcat, m0, n0, As, Bs, acc);

  const int tid = threadIdx.x, w = tid >> 6, lane = tid & 63, lo = lane & 15, hi = lane >> 4;
  const int c1 = (w >> 1) & 1, c2 = w & 1;
  const int h = (nloc >> 6) + c1;
  const int mrow0 = m0 + (w >> 2) * 64;
  if (mode < 2) {
    u16* Out = (mode == 0) ? Qf : Kf;
    const float qscale = (mode == 0) ? 0.18033688011112042f : 1.0f;
    const float invf = exp2f(-(float)(c2 * 16 + lo) * 0.41524101186092034f);
    const int lnoff = (lo >> 3) * 256 + (lo & 7) + c2 * 512;
#pragma unroll
    for (int mi = 0; mi < 4; ++mi) {
#pragma unroll
      for (int r = 0; r < 4; ++r) {
        int tg = mrow0 + mi * 16 + hi * 4 + r;
        int b = tg >> 11, tp = tg & 2047;
        float cs, sn;
        __sincosf((float)tp * invf, &sn, &cs);
        size_t obase = (size_t)((b * 16 + h) * 64 + (tp >> 5)) * 2048 + (size_t)(tp & 31) * 8 + lnoff;
        float v0 = acc[mi][0][r], v1 = acc[mi][1][r];
        Out[obase]        = f2bf((v0 * cs - v1 * sn) * qscale);
        Out[obase + 1024] = f2bf((v1 * cs + v0 * sn) * qscale);
      }
    }
  } else {
#pragma unroll
    for (int mi = 0; mi < 4; ++mi) {
      int tg0 = mrow0 + mi * 16 + hi * 4;
      int b = tg0 >> 11, tp0 = tg0 & 2047;
#pragma unroll
      for (int j = 0; j < 2; ++j) {
        int d = c2 * 16 + j * 32 + lo;
        u16x4 pk;
#pragma unroll
        for (int r = 0; r < 4; ++r) pk[r] = f2bf(acc[mi][j][r]);
        *(u16x4*)(Vf + ((size_t)((b * 16 + h) * 256 + (tp0 >> 3)) * 64 + d) * 8 + (tp0 & 7)) = pk;
      }
    }
  }
}

// ---------- flash attention: 4 independent waves, FIXED-m softmax, NO setprio ----------
// grid (bh=32, qi=64), 256 thr. Wave p takes a quarter of g's 64-key tiles.
// Double K named-set prefetch, (256,2) cap — VGPR 108, 4 waves/SIMD resident.
// EXPERIMENT r18: s_setprio REMOVED. r17 cycle accounting: per-tile issue ~470cy
// but measured ~3000cy/tile with effective ~1.3 waves/SIMD active (occupancy 16%)
// despite 4 resident — hypothesis: continuous prio toggling (all waves identical
// phase) lets the prio-1 wave monopolize issue until stall => near-serial execution
// (T5 requires wave ROLE diversity; m190 showed setprio hurts lockstep kernels).
__global__ __launch_bounds__(256, 2) void attn_kernel(const u16* __restrict__ Qf, const u16* __restrict__ Kf,
                                                      const u16* __restrict__ Vf, u16* __restrict__ ctx) {
  __shared__ u16 Omb[3][32 * 68];
  __shared__ float Lsm[3][32];
  const int bh = blockIdx.x, qi = blockIdx.y;
  const int qr = 63 - qi;
  const int g = (qr & ~7) | (((qr >> 3) & 1) ? (7 - (qr & 7)) : (qr & 7));
  const int tid = threadIdx.x, p = tid >> 6, lane = tid & 63;
  const int lo5 = lane & 31, hi = lane >> 5;
  const int nt = (g >> 1) + 1;
  const int qq = nt >> 2, rem = nt & 3;
  const int cnt = qq + (p < rem ? 1 : 0);
  const int t0 = p * qq + (p < rem ? p : rem);
  const int bb = bh >> 4, h = bh & 15;

  const u16* Qb = Qf + (size_t)bh * 131072 + (size_t)g * 2048 + lane * 8;
  const u16* Kb = Kf + (size_t)bh * 131072 + lane * 8;
  const u16* Vb = Vf + (size_t)bh * 131072 + hi * 512 + lo5 * 8;

  bf16x8 qf[4];
#pragma unroll
  for (int d = 0; d < 4; ++d) qf[d] = *(const bf16x8*)(Qb + d * 512);

  f32x16 O0, O1;
#pragma unroll
  for (int r = 0; r < 16; ++r) { O0[r] = 0.f; O1[r] = 0.f; }
  float l_run = 0.f;

  bf16x8 kA0[4], kB0[4], kA1[4], kB1[4];

  auto LOADK = [&](int t, bf16x8 (&kA)[4], bf16x8 (&kB)[4]) {
    const u16* kt = Kb + (size_t)t * 4096;
#pragma unroll
    for (int d = 0; d < 4; ++d) {
      kA[d] = *(const bf16x8*)(kt + d * 512);
      kB[d] = *(const bf16x8*)(kt + 2048 + d * 512);
    }
  };

  auto COMPUTE = [&](int t, bf16x8 (&kA)[4], bf16x8 (&kB)[4]) {
    f32x16 s0, s1;
#pragma unroll
    for (int r = 0; r < 16; ++r) { s0[r] = 0.f; s1[r] = 0.f; }
#pragma unroll
    for (int d = 0; d < 4; ++d) {
      s0 = __builtin_amdgcn_mfma_f32_32x32x16_bf16(kA[d], qf[d], s0, 0, 0, 0);
      s1 = __builtin_amdgcn_mfma_f32_32x32x16_bf16(kB[d], qf[d], s1, 0, 0, 0);
    }

    const u16* vt = Vb + (size_t)t * 4096;
    bf16x8 vA[4], vB[4];
#pragma unroll
    for (int ks = 0; ks < 4; ++ks) {
      vA[ks] = *(const bf16x8*)(vt + ks * 1024);
      vB[ks] = *(const bf16x8*)(vt + ks * 1024 + 256);
    }

    if (t == nt - 1) {
#pragma unroll
      for (int r = 0; r < 16; ++r) {
        int kl = (r & 3) + 8 * (r >> 2) + 4 * hi;
        if (g & 1) {
          if (kl > lo5) s1[r] = -1e30f;
        } else {
          if (kl > lo5) s0[r] = -1e30f;
          s1[r] = -1e30f;
        }
      }
    }

    float sm[16];
#pragma unroll
    for (int r = 0; r < 16; ++r) {
      float p0 = exp2f(s0[r]); s0[r] = p0;
      float p1 = exp2f(s1[r]); s1[r] = p1;
      sm[r] = p0 + p1;
    }
#pragma unroll
    for (int d = 8; d; d >>= 1)
#pragma unroll
      for (int r = 0; r < d; ++r) sm[r] += sm[r + d];
    l_run += sm[0];

    uint32_t W0[8], W1[8];
#pragma unroll
    for (int i = 0; i < 8; ++i) {
      W0[i] = cvtpk(s0[2 * i], s0[2 * i + 1]);
      W1[i] = cvtpk(s1[2 * i], s1[2 * i + 1]);
    }
#pragma unroll
    for (int ks = 0; ks < 4; ++ks) {
      uint32_t a, d2, c2, e2;
      if (ks == 0)      { a = W0[0]; d2 = W0[1]; c2 = W0[2]; e2 = W0[3]; }
      else if (ks == 1) { a = W0[4]; d2 = W0[5]; c2 = W0[6]; e2 = W0[7]; }
      else if (ks == 2) { a = W1[0]; d2 = W1[1]; c2 = W1[2]; e2 = W1[3]; }
      else              { a = W1[4]; d2 = W1[5]; c2 = W1[6]; e2 = W1[7]; }
      plswap(a, c2);
      plswap(d2, e2);
      union { uint32_t u[4]; bf16x8 v; } f;
      f.u[0] = a; f.u[1] = d2; f.u[2] = c2; f.u[3] = e2;
      O0 = __builtin_amdgcn_mfma_f32_32x32x16_bf16(vA[ks], f.v, O0, 0, 0, 0);
      O1 = __builtin_amdgcn_mfma_f32_32x32x16_bf16(vB[ks], f.v, O1, 0, 0, 0);
    }
  };

  if (cnt > 0) {
    LOADK(t0, kA0, kB0);
    int i = 0;
    for (;;) {
      if (i + 1 < cnt) LOADK(t0 + i + 1, kA1, kB1);
      COMPUTE(t0 + i, kA0, kB0);
      if (++i >= cnt) break;
      if (i + 1 < cnt) LOADK(t0 + i + 1, kA0, kB0);
      COMPUTE(t0 + i, kA1, kB1);
      if (++i >= cnt) break;
    }
  }

  l_run += __shfl_xor(l_run, 32);

  if (p != 0) {
    u16* om = Omb[p - 1] + (size_t)lo5 * 68;
#pragma unroll
    for (int gg = 0; gg < 4; ++gg) {
      int off = 8 * gg + 4 * hi;
      u16x4 w0, w1;
#pragma unroll
      for (int j = 0; j < 4; ++j) { w0[j] = f2bf(O0[4 * gg + j]); w1[j] = f2bf(O1[4 * gg + j]); }
      *(u16x4*)(om + off) = w0;
      *(u16x4*)(om + 32 + off) = w1;
    }
    if (hi == 0) Lsm[p - 1][lo5] = l_run;
  }
  __syncthreads();
  if (p == 0) {
    float invl = 1.0f / (l_run + Lsm[0][lo5] + Lsm[1][lo5] + Lsm[2][lo5]);
    const u16* om1 = Omb[0] + (size_t)lo5 * 68;
    const u16* om2 = Omb[1] + (size_t)lo5 * 68;
    const u16* om3 = Omb[2] + (size_t)lo5 * 68;
    const int tq = 32 * g + lo5;
    size_t rowb = ((size_t)(bb * 2048 + tq)) * 1024 + h * 64;
#pragma unroll
    for (int gg = 0; gg < 4; ++gg) {
      int off = 8 * gg + 4 * hi;
      u16x4 q1 = *(const u16x4*)(om1 + off), q2 = *(const u16x4*)(om2 + off), q3 = *(const u16x4*)(om3 + off);
      u16x4 pk;
#pragma unroll
      for (int j = 0; j < 4; ++j)
        pk[j] = f2bf((O0[4 * gg + j] + bf2f(q1[j]) + bf2f(q2[j]) + bf2f(q3[j])) * invl);
      *(u16x4*)(ctx + rowb + off) = pk;
      u16x4 r1 = *(const u16x4*)(om1 + 32 + off), r2 = *(const u16x4*)(om2 + 32 + off), r3 = *(const u16x4*)(om3 + 32 + off);
#pragma unroll
      for (int j = 0; j < 4; ++j)
        pk[j] = f2bf((O1[4 * gg + j] + bf2f(r1[j]) + bf2f(r2[j]) + bf2f(r3[j])) * invl);
      *(u16x4*)(ctx + rowb + 32 + off) = pk;
    }
  }
}

// ---------- output projection (8-wave): out = ctx @ w_o (f32 out) ----------
__global__ __launch_bounds__(512, 4) void out_gemm_kernel(const u16* __restrict__ ctxb,
                                                          const u16* __restrict__ Wot,
                                                          float* __restrict__ out) {
  __shared__ u16 As[2][4096];
  __shared__ u16 Bs[2][4096];
  const int m0 = blockIdx.x * 128, n0 = blockIdx.y * 128;
  f32x4 acc[4][2];
  const f32x4 z4 = {0.f, 0.f, 0.f, 0.f};
#pragma unroll
  for (int i = 0; i < 4; ++i)
#pragma unroll
    for (int j = 0; j < 2; ++j) acc[i][j] = z4;
  gemm_mainloop8(ctxb, Wot, m0, n0, As, Bs, acc);
  const int tid = threadIdx.x, w = tid >> 6, lane = tid & 63, lo = lane & 15, hi = lane >> 4;
  const int colb = n0 + ((w >> 1) & 1) * 64 + (w & 1) * 16;
#pragma unroll
  for (int mi = 0; mi < 4; ++mi)
#pragma unroll
    for (int r = 0; r < 4; ++r) {
      int tg = m0 + (w >> 2) * 64 + mi * 16 + hi * 4 + r;
      out[(size_t)tg * 1024 + colb + lo] = acc[mi][0][r];
      out[(size_t)tg * 1024 + colb + 32 + lo] = acc[mi][1][r];
    }
}

// ---------- launch ----------
extern "C" void kernel_launch(void* const* d_in, const int* in_sizes, int n_in,
                              void* d_out, int out_size, void* d_ws, size_t ws_size,
                              hipStream_t stream) {
  (void)in_sizes; (void)n_in; (void)out_size; (void)ws_size;
  const float* x  = (const float*)d_in[0];
  const float* wq = (const float*)d_in[1];
  const float* wk = (const float*)d_in[2];
  const float* wv = (const float*)d_in[3];
  const float* wo = (const float*)d_in[4];
  char* ws = (char*)d_ws;
  u16* xb   = (u16*)(ws + (size_t)0);
  u16* Wqt  = (u16*)(ws + ((size_t)8  << 20));   // Wqt/Wkt/Wvt contiguous: 3072x1024
  u16* Wkt  = (u16*)(ws + ((size_t)10 << 20));
  u16* Wvt  = (u16*)(ws + ((size_t)12 << 20));
  u16* Wot  = (u16*)(ws + ((size_t)14 << 20));
  u16* Qf   = (u16*)(ws + ((size_t)16 << 20));
  u16* Kf   = (u16*)(ws + ((size_t)24 << 20));
  u16* Vf   = (u16*)(ws + ((size_t)32 << 20));
  u16* ctxb = (u16*)(ws + ((size_t)40 << 20));

  prep_kernel<<<5120, 256, 0, stream>>>(x, wq, wk, wv, wo, xb, Wqt, Wkt, Wvt, Wot);
  qkv_gemm_kernel<<<dim3(32, 24), 512, 0, stream>>>(xb, Wqt, Qf, Kf, Vf);
  attn_kernel<<<dim3(32, 64), 256, 0, stream>>>(Qf, Kf, Vf, ctxb);
  out_gemm_kernel<<<dim3(32, 8), 512, 0, stream>>>(ctxb, Wot, (float*)d_out);
}

// Round 19
// 102.459 us; speedup vs baseline: 1.7780x; 1.0245x over previous
//
#include <hip/hip_runtime.h>
#include <hip/hip_bf16.h>
#include <cstdint>

using u16 = unsigned short;
typedef short bf16x8 __attribute__((ext_vector_type(8)));
typedef float f32x4 __attribute__((ext_vector_type(4)));
typedef float f32x16 __attribute__((ext_vector_type(16)));
typedef u16 u16x4 __attribute__((ext_vector_type(4)));
typedef u16 u16x8 __attribute__((ext_vector_type(8)));

// ---------- helpers ----------
__device__ __forceinline__ u16 f2bf(float f) {
  union { float f; uint32_t u; } v; v.f = f;
  uint32_t r = (v.u + 0x7fffu + ((v.u >> 16) & 1u)) >> 16;  // RNE
  return (u16)r;
}

__device__ __forceinline__ float bf2f(u16 u) {
  union { uint32_t u; float f; } v; v.u = (uint32_t)u << 16; return v.f;
}

__device__ __forceinline__ void async16(const void* g, void* l) {
  __builtin_amdgcn_global_load_lds(
      (const __attribute__((address_space(1))) uint32_t*)g,
      (__attribute__((address_space(3))) uint32_t*)l, 16, 0, 0);
}

__device__ __forceinline__ uint32_t cvtpk(float a, float b) {
  uint32_t r;
  asm("v_cvt_pk_bf16_f32 %0, %1, %2" : "=v"(r) : "v"(a), "v"(b));
  return r;
}

// swap upper 32 lanes of a with lower 32 lanes of b (validated in PV path since r2)
__device__ __forceinline__ void plswap(uint32_t& a, uint32_t& b) {
  asm volatile("v_permlane32_swap_b32 %0, %1" : "+v"(a), "+v"(b));
}

// ---------- fused prep: cvt x (blocks 0..4095) + 4x weight transpose (4096..5119) ----------
__global__ __launch_bounds__(256) void prep_kernel(
    const float* __restrict__ x, const float* __restrict__ wq, const float* __restrict__ wk,
    const float* __restrict__ wv, const float* __restrict__ wo,
    u16* __restrict__ xb, u16* __restrict__ Wqt, u16* __restrict__ Wkt,
    u16* __restrict__ Wvt, u16* __restrict__ Wot) {
  __shared__ float tile[64][65];
  const int tid = threadIdx.x;
  const int bid = blockIdx.x;
  if (bid < 4096) {
    int i = (bid * 256 + tid) * 4;
    float4 v = *(const float4*)(x + i);
    u16x4 o;
    o[0] = f2bf(v.x); o[1] = f2bf(v.y); o[2] = f2bf(v.z); o[3] = f2bf(v.w);
    *(u16x4*)(xb + i) = o;
    return;
  }
  const int id = bid - 4096;
  const int wsel = id >> 8, sub = id & 255;
  const float* W = (wsel == 0) ? wq : (wsel == 1) ? wk : (wsel == 2) ? wv : wo;
  u16* Wt = (wsel == 0) ? Wqt : (wsel == 1) ? Wkt : (wsel == 2) ? Wvt : Wot;
  const int k0 = (sub & 15) * 64, n0 = (sub >> 4) * 64;
#pragma unroll
  for (int i = 0; i < 4; ++i) {
    int c = i * 256 + tid;
    int r = c >> 4, c4 = c & 15;
    float4 v = *(const float4*)(W + (size_t)(k0 + r) * 1024 + n0 + c4 * 4);
    tile[r][c4 * 4 + 0] = v.x; tile[r][c4 * 4 + 1] = v.y;
    tile[r][c4 * 4 + 2] = v.z; tile[r][c4 * 4 + 3] = v.w;
  }
  __syncthreads();
#pragma unroll
  for (int i = 0; i < 2; ++i) {
    int c = i * 256 + tid;
    int n = c >> 3, kc = c & 7;
    u16x8 o;
#pragma unroll
    for (int j = 0; j < 8; ++j) o[j] = f2bf(tile[kc * 8 + j][n]);
    *(u16x8*)(Wt + (size_t)(n0 + n) * 1024 + k0 + kc * 8) = o;
  }
}

// ---------- 8-wave GEMM mainloop: C(128x128) = A(128xK) * Bt(128xK)^T, K=1024 ----------
__device__ __forceinline__ void stage8(const u16* A, const u16* Bt, int m0, int n0, int kt,
                                       u16* As, u16* Bs, int tid) {
  int row = tid >> 2, cc = tid & 3;
  int koff = kt * 32 + ((cc ^ (row & 3)) << 3);
  async16(A + (size_t)(m0 + row) * 1024 + koff, As + (size_t)tid * 8);
  async16(Bt + (size_t)(n0 + row) * 1024 + koff, Bs + (size_t)tid * 8);
}

__device__ __forceinline__ void gemm_mainloop8(const u16* A, const u16* Bt, int m0, int n0,
                                               u16 (*As)[4096], u16 (*Bs)[4096], f32x4 acc[4][2]) {
  const int tid = threadIdx.x, w = tid >> 6, lane = tid & 63, lo = lane & 15, hi = lane >> 4;
  const int mb = (w >> 2) * 64;
  const int cb = ((w >> 1) & 1) * 64 + (w & 1) * 16;
  stage8(A, Bt, m0, n0, 0, As[0], Bs[0], tid);
  __syncthreads();
  for (int kt = 0; kt < 32; ++kt) {
    int cur = kt & 1;
    if (kt + 1 < 32) stage8(A, Bt, m0, n0, kt + 1, As[cur ^ 1], Bs[cur ^ 1], tid);
    const int sw = (hi ^ (lo & 3)) << 3;
    bf16x8 af[4], bfr[2];
#pragma unroll
    for (int i = 0; i < 4; ++i) af[i] = *(const bf16x8*)(As[cur] + (mb + i * 16 + lo) * 32 + sw);
#pragma unroll
    for (int j = 0; j < 2; ++j) bfr[j] = *(const bf16x8*)(Bs[cur] + (cb + j * 32 + lo) * 32 + sw);
#pragma unroll
    for (int i = 0; i < 4; ++i)
#pragma unroll
      for (int j = 0; j < 2; ++j)
        acc[i][j] = __builtin_amdgcn_mfma_f32_16x16x32_bf16(af[i], bfr[j], acc[i][j], 0, 0, 0);
    __syncthreads();
  }
}

// ---------- FUSED QKV projection + RoPE + scatter (8-wave) ----------
__global__ __launch_bounds__(512, 4) void qkv_gemm_kernel(
    const u16* __restrict__ xb, const u16* __restrict__ Wcat,
    u16* __restrict__ Qf, u16* __restrict__ Kf, u16* __restrict__ Vf) {
  __shared__ u16 As[2][4096];
  __shared__ u16 Bs[2][4096];
  const int m0 = blockIdx.x * 128, n0 = blockIdx.y * 128;
  const int mode = n0 >> 10, nloc = n0 & 1023;
  f32x4 acc[4][2];
  const f32x4 z4 = {0.f, 0.f, 0.f, 0.f};
#pragma unroll
  for (int i = 0; i < 4; ++i)
#pragma unroll
    for (int j = 0; j < 2; ++j) acc[i][j] = z4;
  gemm_mainloop8(xb, Wcat, m0, n0, As, Bs, acc);

  const int tid = threadIdx.x, w = tid >> 6, lane = tid & 63, lo = lane & 15, hi = lane >> 4;
  const int c1 = (w >> 1) & 1, c2 = w & 1;
  const int h = (nloc >> 6) + c1;
  const int mrow0 = m0 + (w >> 2) * 64;
  if (mode < 2) {
    u16* Out = (mode == 0) ? Qf : Kf;
    const float qscale = (mode == 0) ? 0.18033688011112042f : 1.0f;
    const float invf = exp2f(-(float)(c2 * 16 + lo) * 0.41524101186092034f);
    const int lnoff = (lo >> 3) * 256 + (lo & 7) + c2 * 512;
#pragma unroll
    for (int mi = 0; mi < 4; ++mi) {
#pragma unroll
      for (int r = 0; r < 4; ++r) {
        int tg = mrow0 + mi * 16 + hi * 4 + r;
        int b = tg >> 11, tp = tg & 2047;
        float cs, sn;
        __sincosf((float)tp * invf, &sn, &cs);
        size_t obase = (size_t)((b * 16 + h) * 64 + (tp >> 5)) * 2048 + (size_t)(tp & 31) * 8 + lnoff;
        float v0 = acc[mi][0][r], v1 = acc[mi][1][r];
        Out[obase]        = f2bf((v0 * cs - v1 * sn) * qscale);
        Out[obase + 1024] = f2bf((v1 * cs + v0 * sn) * qscale);
      }
    }
  } else {
#pragma unroll
    for (int mi = 0; mi < 4; ++mi) {
      int tg0 = mrow0 + mi * 16 + hi * 4;
      int b = tg0 >> 11, tp0 = tg0 & 2047;
#pragma unroll
      for (int j = 0; j < 2; ++j) {
        int d = c2 * 16 + j * 32 + lo;
        u16x4 pk;
#pragma unroll
        for (int r = 0; r < 4; ++r) pk[r] = f2bf(acc[mi][j][r]);
        *(u16x4*)(Vf + ((size_t)((b * 16 + h) * 256 + (tp0 >> 3)) * 64 + d) * 8 + (tp0 & 7)) = pk;
      }
    }
  }
}

// ---------- flash attention: 4 independent waves, FIXED-m softmax, SINGLE K set ----------
// grid (bh=32, qi=64), 256 thr. Wave p takes a quarter of g's 64-key tiles.
// r19 single-variable test: K prefetch in ONE named set under the PROVEN (256,2)
// cap (r15's failure was the (256,4) cap -> scratch spill, not the single set;
// single-set correctness passed r15). Live set drops ~144 -> ~112, inside the
// allocator's observed ~128-reg target -> less v_accvgpr ping-pong (suspected
// source of the 2x VALU inflation: VALUBusy ~50% at only ~470cy/tile issue work).
// LOADK(t+1) issues right after QK's MFMAs consume kA/kB: ~600cy of flight.
__global__ __launch_bounds__(256, 2) void attn_kernel(const u16* __restrict__ Qf, const u16* __restrict__ Kf,
                                                      const u16* __restrict__ Vf, u16* __restrict__ ctx) {
  __shared__ u16 Omb[3][32 * 68];
  __shared__ float Lsm[3][32];
  const int bh = blockIdx.x, qi = blockIdx.y;
  const int qr = 63 - qi;
  const int g = (qr & ~7) | (((qr >> 3) & 1) ? (7 - (qr & 7)) : (qr & 7));
  const int tid = threadIdx.x, p = tid >> 6, lane = tid & 63;
  const int lo5 = lane & 31, hi = lane >> 5;
  const int nt = (g >> 1) + 1;
  const int qq = nt >> 2, rem = nt & 3;
  const int cnt = qq + (p < rem ? 1 : 0);
  const int t0 = p * qq + (p < rem ? p : rem);
  const int bb = bh >> 4, h = bh & 15;

  const u16* Qb = Qf + (size_t)bh * 131072 + (size_t)g * 2048 + lane * 8;
  const u16* Kb = Kf + (size_t)bh * 131072 + lane * 8;
  const u16* Vb = Vf + (size_t)bh * 131072 + hi * 512 + lo5 * 8;

  bf16x8 qf[4];
#pragma unroll
  for (int d = 0; d < 4; ++d) qf[d] = *(const bf16x8*)(Qb + d * 512);

  f32x16 O0, O1;
#pragma unroll
  for (int r = 0; r < 16; ++r) { O0[r] = 0.f; O1[r] = 0.f; }
  float l_run = 0.f;

  bf16x8 kA[4], kB[4];  // single K register set

  auto LOADK = [&](int t) {
    const u16* kt = Kb + (size_t)t * 4096;
#pragma unroll
    for (int d = 0; d < 4; ++d) {
      kA[d] = *(const bf16x8*)(kt + d * 512);
      kB[d] = *(const bf16x8*)(kt + 2048 + d * 512);
    }
  };

  if (cnt > 0) {
    LOADK(t0);
    for (int i = 0; i < cnt; ++i) {
      const int t = t0 + i;
      f32x16 s0, s1;
#pragma unroll
      for (int r = 0; r < 16; ++r) { s0[r] = 0.f; s1[r] = 0.f; }
#pragma unroll
      for (int d = 0; d < 4; ++d) {
        s0 = __builtin_amdgcn_mfma_f32_32x32x16_bf16(kA[d], qf[d], s0, 0, 0, 0);
        s1 = __builtin_amdgcn_mfma_f32_32x32x16_bf16(kB[d], qf[d], s1, 0, 0, 0);
      }

      // prefetch next K into the SAME set (QK consumed it at issue); lands under
      // the V-load + exp + pack + PV phase (~600cy)
      if (i + 1 < cnt) LOADK(t + 1);

      const u16* vt = Vb + (size_t)t * 4096;
      bf16x8 vA[4], vB[4];
#pragma unroll
      for (int ks = 0; ks < 4; ++ks) {
        vA[ks] = *(const bf16x8*)(vt + ks * 1024);
        vB[ks] = *(const bf16x8*)(vt + ks * 1024 + 256);
      }

      if (t == nt - 1) {
#pragma unroll
        for (int r = 0; r < 16; ++r) {
          int kl = (r & 3) + 8 * (r >> 2) + 4 * hi;
          if (g & 1) {
            if (kl > lo5) s1[r] = -1e30f;
          } else {
            if (kl > lo5) s0[r] = -1e30f;
            s1[r] = -1e30f;
          }
        }
      }

      float sm[16];
#pragma unroll
      for (int r = 0; r < 16; ++r) {
        float p0 = exp2f(s0[r]); s0[r] = p0;
        float p1 = exp2f(s1[r]); s1[r] = p1;
        sm[r] = p0 + p1;
      }
#pragma unroll
      for (int d = 8; d; d >>= 1)
#pragma unroll
        for (int r = 0; r < d; ++r) sm[r] += sm[r + d];
      l_run += sm[0];

      uint32_t W0[8], W1[8];
#pragma unroll
      for (int i2 = 0; i2 < 8; ++i2) {
        W0[i2] = cvtpk(s0[2 * i2], s0[2 * i2 + 1]);
        W1[i2] = cvtpk(s1[2 * i2], s1[2 * i2 + 1]);
      }
#pragma unroll
      for (int ks = 0; ks < 4; ++ks) {
        uint32_t a, d2, c2, e2;
        if (ks == 0)      { a = W0[0]; d2 = W0[1]; c2 = W0[2]; e2 = W0[3]; }
        else if (ks == 1) { a = W0[4]; d2 = W0[5]; c2 = W0[6]; e2 = W0[7]; }
        else if (ks == 2) { a = W1[0]; d2 = W1[1]; c2 = W1[2]; e2 = W1[3]; }
        else              { a = W1[4]; d2 = W1[5]; c2 = W1[6]; e2 = W1[7]; }
        plswap(a, c2);
        plswap(d2, e2);
        union { uint32_t u[4]; bf16x8 v; } f;
        f.u[0] = a; f.u[1] = d2; f.u[2] = c2; f.u[3] = e2;
        O0 = __builtin_amdgcn_mfma_f32_32x32x16_bf16(vA[ks], f.v, O0, 0, 0, 0);
        O1 = __builtin_amdgcn_mfma_f32_32x32x16_bf16(vB[ks], f.v, O1, 0, 0, 0);
      }
    }
  }

  l_run += __shfl_xor(l_run, 32);

  if (p != 0) {
    u16* om = Omb[p - 1] + (size_t)lo5 * 68;
#pragma unroll
    for (int gg = 0; gg < 4; ++gg) {
      int off = 8 * gg + 4 * hi;
      u16x4 w0, w1;
#pragma unroll
      for (int j = 0; j < 4; ++j) { w0[j] = f2bf(O0[4 * gg + j]); w1[j] = f2bf(O1[4 * gg + j]); }
      *(u16x4*)(om + off) = w0;
      *(u16x4*)(om + 32 + off) = w1;
    }
    if (hi == 0) Lsm[p - 1][lo5] = l_run;
  }
  __syncthreads();
  if (p == 0) {
    float invl = 1.0f / (l_run + Lsm[0][lo5] + Lsm[1][lo5] + Lsm[2][lo5]);
    const u16* om1 = Omb[0] + (size_t)lo5 * 68;
    const u16* om2 = Omb[1] + (size_t)lo5 * 68;
    const u16* om3 = Omb[2] + (size_t)lo5 * 68;
    const int tq = 32 * g + lo5;
    size_t rowb = ((size_t)(bb * 2048 + tq)) * 1024 + h * 64;
#pragma unroll
    for (int gg = 0; gg < 4; ++gg) {
      int off = 8 * gg + 4 * hi;
      u16x4 q1 = *(const u16x4*)(om1 + off), q2 = *(const u16x4*)(om2 + off), q3 = *(const u16x4*)(om3 + off);
      u16x4 pk;
#pragma unroll
      for (int j = 0; j < 4; ++j)
        pk[j] = f2bf((O0[4 * gg + j] + bf2f(q1[j]) + bf2f(q2[j]) + bf2f(q3[j])) * invl);
      *(u16x4*)(ctx + rowb + off) = pk;
      u16x4 r1 = *(const u16x4*)(om1 + 32 + off), r2 = *(const u16x4*)(om2 + 32 + off), r3 = *(const u16x4*)(om3 + 32 + off);
#pragma unroll
      for (int j = 0; j < 4; ++j)
        pk[j] = f2bf((O1[4 * gg + j] + bf2f(r1[j]) + bf2f(r2[j]) + bf2f(r3[j])) * invl);
      *(u16x4*)(ctx + rowb + 32 + off) = pk;
    }
  }
}

// ---------- output projection (8-wave): out = ctx @ w_o (f32 out) ----------
__global__ __launch_bounds__(512, 4) void out_gemm_kernel(const u16* __restrict__ ctxb,
                                                          const u16* __restrict__ Wot,
                                                          float* __restrict__ out) {
  __shared__ u16 As[2][4096];
  __shared__ u16 Bs[2][4096];
  const int m0 = blockIdx.x * 128, n0 = blockIdx.y * 128;
  f32x4 acc[4][2];
  const f32x4 z4 = {0.f, 0.f, 0.f, 0.f};
#pragma unroll
  for (int i = 0; i < 4; ++i)
#pragma unroll
    for (int j = 0; j < 2; ++j) acc[i][j] = z4;
  gemm_mainloop8(ctxb, Wot, m0, n0, As, Bs, acc);
  const int tid = threadIdx.x, w = tid >> 6, lane = tid & 63, lo = lane & 15, hi = lane >> 4;
  const int colb = n0 + ((w >> 1) & 1) * 64 + (w & 1) * 16;
#pragma unroll
  for (int mi = 0; mi < 4; ++mi)
#pragma unroll
    for (int r = 0; r < 4; ++r) {
      int tg = m0 + (w >> 2) * 64 + mi * 16 + hi * 4 + r;
      out[(size_t)tg * 1024 + colb + lo] = acc[mi][0][r];
      out[(size_t)tg * 1024 + colb + 32 + lo] = acc[mi][1][r];
    }
}

// ---------- launch ----------
extern "C" void kernel_launch(void* const* d_in, const int* in_sizes, int n_in,
                              void* d_out, int out_size, void* d_ws, size_t ws_size,
                              hipStream_t stream) {
  (void)in_sizes; (void)n_in; (void)out_size; (void)ws_size;
  const float* x  = (const float*)d_in[0];
  const float* wq = (const float*)d_in[1];
  const float* wk = (const float*)d_in[2];
  const float* wv = (const float*)d_in[3];
  const float* wo = (const float*)d_in[4];
  char* ws = (char*)d_ws;
  u16* xb   = (u16*)(ws + (size_t)0);
  u16* Wqt  = (u16*)(ws + ((size_t)8  << 20));   // Wqt/Wkt/Wvt contiguous: 3072x1024
  u16* Wkt  = (u16*)(ws + ((size_t)10 << 20));
  u16* Wvt  = (u16*)(ws + ((size_t)12 << 20));
  u16* Wot  = (u16*)(ws + ((size_t)14 << 20));
  u16* Qf   = (u16*)(ws + ((size_t)16 << 20));
  u16* Kf   = (u16*)(ws + ((size_t)24 << 20));
  u16* Vf   = (u16*)(ws + ((size_t)32 << 20));
  u16* ctxb = (u16*)(ws + ((size_t)40 << 20));

  prep_kernel<<<5120, 256, 0, stream>>>(x, wq, wk, wv, wo, xb, Wqt, Wkt, Wvt, Wot);
  qkv_gemm_kernel<<<dim3(32, 24), 512, 0, stream>>>(xb, Wqt, Qf, Kf, Vf);
  attn_kernel<<<dim3(32, 64), 256, 0, stream>>>(Qf, Kf, Vf, ctxb);
  out_gemm_kernel<<<dim3(32, 8), 512, 0, stream>>>(ctxb, Wot, (float*)d_out);
}